// Round 1
// baseline (646.393 us; speedup 1.0000x reference)
//
#include <hip/hip_runtime.h>
#include <math.h>

// Problem dims
#define NN   2048      // nodes
#define BB   64        // batch
#define FF   48        // in features
#define EE   65536     // edges per graph
#define CC   7         // out channels
#define HH   20        // hidden
#define MM   (NN*BB)   // 131072 dense rows

// ---- ws layout (bytes) ----
// zero region (memset each call): deg[4][N] int, cursor[4][N] int, S_gnn[N*B*C] f32, S_dense[N*B*C] f32
#define OFF_DEG      0u
#define OFF_CURSOR   32768u
#define OFF_SGNN     65536u
#define OFF_SDENSE   3735552u
#define ZBYTES       7405568u
#define OFF_DINV     7405568u          // float[4][N]
#define OFF_ROWPTR   7438336u          // int[4][N+1]
#define OFF_CSRC     7471360u          // int[4][E]
#define OFF_CSRW     8519936u          // float[4][E]
#define OFF_H1       9568512u          // float[N*B*H] 10.5MB
#define OFF_XV       20054272u         // float[N*B*H]
#define OFF_Y        30540032u         // float[N*B*H]
#define OFF_H2       41025792u         // float[N*B*C]
#define OFF_YV       44695808u         // float[N*B*C]
#define OFF_T        OFF_H1            // float[M*40] 21MB, overlays H1+XV (dead by then)
// total needed: 48,365,824 B

// ---------------- CSR build ----------------
__global__ __launch_bounds__(256) void count_deg_kernel(
    const int* __restrict__ c0, const int* __restrict__ c1,
    const int* __restrict__ c2, const int* __restrict__ c3, int* __restrict__ deg)
{
    int idx = blockIdx.x * 256 + threadIdx.x;          // 4*E threads
    int g = idx >> 16, e = idx & 0xFFFF;
    const int* cp = g == 0 ? c0 : g == 1 ? c1 : g == 2 ? c2 : c3;
    atomicAdd(&deg[(g << 11) + cp[e]], 1);
}

__global__ __launch_bounds__(256) void scan_dinv_kernel(
    const int* __restrict__ deg, int* __restrict__ rowptr, float* __restrict__ dinv)
{
    int g = blockIdx.x, t = threadIdx.x;
    __shared__ int part[256];
    const int* d = deg + g * NN;
    int loc[8]; int s = 0;
#pragma unroll
    for (int j = 0; j < 8; ++j) { loc[j] = d[t * 8 + j]; s += loc[j]; }
    part[t] = s; __syncthreads();
    for (int off = 1; off < 256; off <<= 1) {
        int v = (t >= off) ? part[t - off] : 0;
        __syncthreads();
        part[t] += v;
        __syncthreads();
    }
    int run = (t > 0) ? part[t - 1] : 0;
    int* rp = rowptr + g * (NN + 1);
#pragma unroll
    for (int j = 0; j < 8; ++j) {
        int n = t * 8 + j;
        rp[n] = run; run += loc[j];
        dinv[g * NN + n] = loc[j] > 0 ? 1.0f / sqrtf((float)loc[j]) : 0.0f;
    }
    if (t == 255) rp[NN] = run;
}

__global__ __launch_bounds__(256) void fill_csr_kernel(
    const int* __restrict__ r0, const int* __restrict__ c0,
    const int* __restrict__ r1, const int* __restrict__ c1,
    const int* __restrict__ r2, const int* __restrict__ c2,
    const int* __restrict__ r3, const int* __restrict__ c3,
    const int* __restrict__ rowptr, int* __restrict__ cursor,
    const float* __restrict__ dinv, int* __restrict__ csrc, float* __restrict__ cw)
{
    int idx = blockIdx.x * 256 + threadIdx.x;
    int g = idx >> 16, e = idx & 0xFFFF;
    const int* rp = g == 0 ? r0 : g == 1 ? r1 : g == 2 ? r2 : r3;
    const int* cp = g == 0 ? c0 : g == 1 ? c1 : g == 2 ? c2 : c3;
    int r = rp[e], c = cp[e];
    int pos = atomicAdd(&cursor[(g << 11) + c], 1);
    int o = rowptr[g * (NN + 1) + c] + pos;
    csrc[(g << 16) + o] = r;
    cw[(g << 16) + o] = dinv[(g << 11) + r] * dinv[(g << 11) + c];
}

// ---------------- dual GEMM: [M,48] @ [48,20] x2 ----------------
// 256 rows/block, 4 rows/thread, 4 k-groups of 5. LDS x-tile stride 49 (conflict-free).
__global__ __launch_bounds__(256) void gemm48_dual(
    const float* __restrict__ X,
    const float* __restrict__ Wa, const float* __restrict__ Wb, int wstride,
    const float* __restrict__ ba, const float* __restrict__ bb,
    float* __restrict__ outA, float* __restrict__ outB, int ostride)
{
    __shared__ float xs[256 * 49];
    __shared__ float was[48 * 20], wbs[48 * 20];
    __shared__ float bas[20], bbs[20];
    int t = threadIdx.x;
    size_t base = (size_t)blockIdx.x * 256 * 48;

    // stage X tile: 12288 floats as 3072 float4 global loads, scalar LDS writes
    {
        int fl = 4 * t;
        int r = fl / 48, f = fl % 48;
#pragma unroll
        for (int i = 0; i < 12; ++i) {
            float4 v = *reinterpret_cast<const float4*>(&X[base + (size_t)r * 48 + f]);
            float* p = &xs[r * 49 + f];
            p[0] = v.x; p[1] = v.y; p[2] = v.z; p[3] = v.w;
            r += 21; f += 16;
            if (f >= 48) { f -= 48; r += 1; }
        }
    }
    for (int i = t; i < 960; i += 256) {
        int wf = i / 20, wk = i - wf * 20;
        was[i] = Wa[wf * wstride + wk];
        wbs[i] = Wb[wf * wstride + wk];
    }
    if (t < 20) {
        bas[t] = ba ? ba[t] : 0.0f;
        bbs[t] = bb ? bb[t] : 0.0f;
    }
    __syncthreads();

    int kg = t & 3, rg = t >> 2;
    int r0 = rg * 4, kb = kg * 5;
    float accA[4][5] = {}; float accB[4][5] = {};
    for (int f = 0; f < 48; ++f) {
        float x0 = xs[(r0 + 0) * 49 + f];
        float x1 = xs[(r0 + 1) * 49 + f];
        float x2 = xs[(r0 + 2) * 49 + f];
        float x3 = xs[(r0 + 3) * 49 + f];
#pragma unroll
        for (int j = 0; j < 5; ++j) {
            float wa = was[f * 20 + kb + j];
            float wb = wbs[f * 20 + kb + j];
            accA[0][j] += x0 * wa; accA[1][j] += x1 * wa;
            accA[2][j] += x2 * wa; accA[3][j] += x3 * wa;
            accB[0][j] += x0 * wb; accB[1][j] += x1 * wb;
            accB[2][j] += x2 * wb; accB[3][j] += x3 * wb;
        }
    }
    size_t orow = (size_t)blockIdx.x * 256 + r0;
#pragma unroll
    for (int i = 0; i < 4; ++i)
#pragma unroll
        for (int j = 0; j < 5; ++j) {
            outA[(orow + i) * ostride + kb + j] = accA[i][j] + bas[kb + j];
            outB[(orow + i) * ostride + kb + j] = accB[i][j] + bbs[kb + j];
        }
}

// ---------------- SpMM layer 1 + GELU + ELU ----------------
// One (node, batch-chunk-of-16) per block; chunk-major grid so each 2.6MB H1
// slice is per-XCD-L2-resident during the gather.
__global__ __launch_bounds__(320) void spmm1_kernel(
    const float* __restrict__ H1, const float* __restrict__ XV, float* __restrict__ Y,
    const int* __restrict__ rowptr, const int* __restrict__ src, const float* __restrict__ wts)
{
    int n = blockIdx.x & (NN - 1);
    int q = blockIdx.x >> 11;
    int off = q * 320 + threadIdx.x;
    int s0 = rowptr[n], s1 = rowptr[n + 1];
    float acc = 0.0f;
    int e = s0;
    for (; e + 1 < s1; e += 2) {
        int sA = src[e], sB = src[e + 1];
        float wA = wts[e], wB = wts[e + 1];
        acc += wA * H1[(size_t)sA * 1280 + off];
        acc += wB * H1[(size_t)sB * 1280 + off];
    }
    if (e < s1) acc += wts[e] * H1[(size_t)src[e] * 1280 + off];

    size_t b0 = (size_t)n * 1280 + off;
    float v = acc + XV[b0];
    float g = 0.5f * v * (1.0f + erff(v * 0.70710678118654752f));   // exact GELU
    Y[b0] = g > 0.0f ? g : expm1f(g);                                // ELU
}

// ---------------- dual GEMM 2: [M,20] @ [20,7] x2 ----------------
__global__ __launch_bounds__(256) void gemm2_dual(
    const float* __restrict__ Y, const float* __restrict__ W2,
    const float* __restrict__ V2, const float* __restrict__ b2,
    float* __restrict__ H2, float* __restrict__ YV)
{
    __shared__ float w2s[140], v2s[140], b2s[7];
    int t = threadIdx.x;
    if (t < 140) { w2s[t] = W2[t]; v2s[t] = V2[t]; }
    if (t < 7) b2s[t] = b2[t];
    __syncthreads();
    size_t row = (size_t)blockIdx.x * 256 + t;
    float y[20];
#pragma unroll
    for (int j = 0; j < 5; ++j)
        *reinterpret_cast<float4*>(&y[j * 4]) = *reinterpret_cast<const float4*>(&Y[row * 20 + j * 4]);
    float a[7] = {}, b[7] = {};
#pragma unroll
    for (int k = 0; k < 20; ++k) {
        float yk = y[k];
#pragma unroll
        for (int c = 0; c < 7; ++c) {
            a[c] += yk * w2s[k * 7 + c];
            b[c] += yk * v2s[k * 7 + c];
        }
    }
#pragma unroll
    for (int c = 0; c < 7; ++c) {
        H2[row * 7 + c] = a[c];
        YV[row * 7 + c] = b[c] + b2s[c];
    }
}

// ---------------- wave softmax over 64 lanes (axis 0 of [B,N,C]) ----------------
__device__ __forceinline__ void wave_softmax7(float* z)
{
#pragma unroll
    for (int c = 0; c < 7; ++c) {
        float m = z[c];
#pragma unroll
        for (int o = 32; o > 0; o >>= 1) m = fmaxf(m, __shfl_xor(m, o, 64));
        float p = expf(z[c] - m);
        float s = p;
#pragma unroll
        for (int o = 32; o > 0; o >>= 1) s += __shfl_xor(s, o, 64);
        z[c] = p / s;
    }
}

// ---------------- SpMM layer 2 + ReLU + softmax(B) + accumulate ----------------
__global__ __launch_bounds__(256) void spmm2_kernel(
    const float* __restrict__ H2, const float* __restrict__ YV,
    const int* __restrict__ rowptr, const int* __restrict__ src, const float* __restrict__ wts,
    float* __restrict__ S, float coef)
{
    int wv = threadIdx.x >> 6, b = threadIdx.x & 63;
    int n = blockIdx.x * 4 + wv;
    int s0 = rowptr[n], s1 = rowptr[n + 1];
    float acc[7] = {};
    for (int e = s0; e < s1; ++e) {
        const float* hp = H2 + (size_t)src[e] * 448 + b * 7;
        float w = wts[e];
#pragma unroll
        for (int c = 0; c < 7; ++c) acc[c] += w * hp[c];
    }
    size_t base = (size_t)n * 448 + b * 7;
    float z[7];
#pragma unroll
    for (int c = 0; c < 7; ++c) {
        float v = acc[c] + YV[base + c];
        z[c] = v > 0.0f ? v : 0.0f;
    }
    wave_softmax7(z);
#pragma unroll
    for (int c = 0; c < 7; ++c) S[base + c] += coef * z[c];
}

// ---------------- final: o_lt tail, dense+gnn heads, output ----------------
__global__ __launch_bounds__(256) void combine_kernel(
    const float* __restrict__ T, const float* __restrict__ Sd, const float* __restrict__ Sg,
    const float* __restrict__ Wl2, const float* __restrict__ bl2,
    const float* __restrict__ Wd, const float* __restrict__ bd,
    const float* __restrict__ Wg, const float* __restrict__ bg,
    float* __restrict__ out)
{
    __shared__ float wl2s[280], bl2s[7], wds[49], bds[7], wgs[49], bgs[7];
    int t = threadIdx.x;
    for (int i = t; i < 280; i += 256) wl2s[i] = Wl2[i];
    if (t < 49) { wds[t] = Wd[t]; wgs[t] = Wg[t]; }
    if (t < 7) { bl2s[t] = bl2[t]; bds[t] = bd[t]; bgs[t] = bg[t]; }
    __syncthreads();

    int wv = t >> 6, b = t & 63;
    int n = blockIdx.x * 4 + wv;
    size_t rbase = ((size_t)n * 64 + b) * 40;
    float tr[40];
#pragma unroll
    for (int j = 0; j < 10; ++j)
        *reinterpret_cast<float4*>(&tr[j * 4]) = *reinterpret_cast<const float4*>(&T[rbase + j * 4]);

    float u[7];
#pragma unroll
    for (int c = 0; c < 7; ++c) u[c] = bl2s[c];
    for (int j = 0; j < 40; ++j) {
        float tv = tr[j];
#pragma unroll
        for (int c = 0; c < 7; ++c) u[c] += tv * wl2s[j * 7 + c];
    }
    wave_softmax7(u);   // o_lt

    size_t sbase = (size_t)n * 448 + b * 7;
    float sd[7], dv[7];
#pragma unroll
    for (int c = 0; c < 7; ++c) sd[c] = Sd[sbase + c] + 2.0f * u[c];
#pragma unroll
    for (int c = 0; c < 7; ++c) dv[c] = bds[c];
#pragma unroll
    for (int c2 = 0; c2 < 7; ++c2) {
        float s = sd[c2];
#pragma unroll
        for (int c = 0; c < 7; ++c) dv[c] += s * wds[c2 * 7 + c];
    }
    wave_softmax7(dv);  // out_dense

    float sg[7], gv[7];
#pragma unroll
    for (int c = 0; c < 7; ++c) sg[c] = Sg[sbase + c];
#pragma unroll
    for (int c = 0; c < 7; ++c) gv[c] = bgs[c];
#pragma unroll
    for (int c2 = 0; c2 < 7; ++c2) {
        float s = sg[c2];
#pragma unroll
        for (int c = 0; c < 7; ++c) gv[c] += s * wgs[c2 * 7 + c];
    }
    wave_softmax7(gv);  // out_gnn

    size_t ob = (size_t)n * 448;
#pragma unroll
    for (int c = 0; c < 7; ++c) out[ob + (size_t)c * 64 + b] = dv[c] + gv[c];
}

// ---------------- host ----------------
extern "C" void kernel_launch(void* const* d_in, const int* in_sizes, int n_in,
                              void* d_out, int out_size, void* d_ws, size_t ws_size,
                              hipStream_t stream)
{
    (void)in_sizes; (void)n_in; (void)out_size; (void)ws_size;
    const int* e0 = (const int*)d_in[0];
    const int* e1 = (const int*)d_in[1];
    const int* e2 = (const int*)d_in[2];
    const int* e3 = (const int*)d_in[3];
    const float* Xin[6] = {
        (const float*)d_in[4], (const float*)d_in[5], (const float*)d_in[6],
        (const float*)d_in[7], (const float*)d_in[8], (const float*)d_in[9] };
    const float* W1  = (const float*)d_in[10];
    const float* V1  = (const float*)d_in[11];
    const float* b1  = (const float*)d_in[12];
    const float* W2  = (const float*)d_in[13];
    const float* V2  = (const float*)d_in[14];
    const float* b2  = (const float*)d_in[15];
    const float* Wlt = (const float*)d_in[16];
    const float* blt = (const float*)d_in[17];
    const float* Wl2 = (const float*)d_in[18];
    const float* bl2 = (const float*)d_in[19];
    const float* Wd  = (const float*)d_in[20];
    const float* bd  = (const float*)d_in[21];
    const float* Wg  = (const float*)d_in[22];
    const float* bg  = (const float*)d_in[23];

    char* ws = (char*)d_ws;
    int*   deg    = (int*)(ws + OFF_DEG);
    int*   cursor = (int*)(ws + OFF_CURSOR);
    float* Sgnn   = (float*)(ws + OFF_SGNN);
    float* Sdense = (float*)(ws + OFF_SDENSE);
    float* dinv   = (float*)(ws + OFF_DINV);
    int*   rowptr = (int*)(ws + OFF_ROWPTR);
    int*   csrc   = (int*)(ws + OFF_CSRC);
    float* csrw   = (float*)(ws + OFF_CSRW);
    float* H1     = (float*)(ws + OFF_H1);
    float* XV     = (float*)(ws + OFF_XV);
    float* Y      = (float*)(ws + OFF_Y);
    float* H2     = (float*)(ws + OFF_H2);
    float* YV     = (float*)(ws + OFF_YV);
    float* Tbuf   = (float*)(ws + OFF_T);

    // zero accumulators + counters (deg, cursor, S_gnn, S_dense are contiguous)
    hipMemsetAsync(d_ws, 0, ZBYTES, stream);

    count_deg_kernel<<<1024, 256, 0, stream>>>(e0 + EE, e1 + EE, e2 + EE, e3 + EE, deg);
    scan_dinv_kernel<<<4, 256, 0, stream>>>(deg, rowptr, dinv);
    fill_csr_kernel<<<1024, 256, 0, stream>>>(e0, e0 + EE, e1, e1 + EE, e2, e2 + EE,
                                              e3, e3 + EE, rowptr, cursor, dinv, csrc, csrw);

    const int GOF[6] = { 0, 1, 2, 0, 0, 3 };
    for (int i = 0; i < 6; ++i) {
        int g = GOF[i];
        const int*   rp = rowptr + g * (NN + 1);
        const int*   sc = csrc + (size_t)g * EE;
        const float* cw = csrw + (size_t)g * EE;
        gemm48_dual<<<512, 256, 0, stream>>>(Xin[i], W1 + i * 960, V1 + i * 960, 20,
                                             nullptr, b1 + i * 20, H1, XV, 20);
        spmm1_kernel<<<8192, 320, 0, stream>>>(H1, XV, Y, rp, sc, cw);
        gemm2_dual<<<512, 256, 0, stream>>>(Y, W2 + i * 140, V2 + i * 140, b2 + i * 7, H2, YV);
        spmm2_kernel<<<512, 256, 0, stream>>>(H2, YV, rp, sc, cw,
                                              i < 5 ? Sgnn : Sdense, i < 5 ? 1.0f : 2.0f);
    }
    // o_lt linear part: T = Xlt@Wlt + blt  (two 20-wide halves of the 40-wide output)
    gemm48_dual<<<512, 256, 0, stream>>>(Xin[5], Wlt, Wlt + 20, 40,
                                         blt, blt + 20, Tbuf, Tbuf + 20, 40);
    combine_kernel<<<512, 256, 0, stream>>>(Tbuf, Sdense, Sgnn, Wl2, bl2, Wd, bd, Wg, bg,
                                            (float*)d_out);
}

// Round 2
// 506.437 us; speedup vs baseline: 1.2764x; 1.2764x over previous
//
#include <hip/hip_runtime.h>
#include <math.h>

// Problem dims
#define NN   2048      // nodes
#define BB   64        // batch
#define FF   48        // in features
#define EE   65536     // edges per graph
#define CC   7         // out channels
#define HH   20        // hidden
#define MM   (NN*BB)   // 131072 dense rows

// ---- ws layout (bytes) ----
// zero region (memset each call): deg[4][N] int, cursor[4][N] int, S_gnn, S_dense
#define OFF_DEG      0u
#define OFF_CURSOR   32768u
#define OFF_SGNN     65536u
#define OFF_SDENSE   3735552u
#define ZBYTES       7405568u
#define OFF_DINV     7405568u          // float[4][N]
#define OFF_ROWPTR   7438336u          // int[4][N+1]
#define OFF_CSRC     7471360u          // int[4][E]
#define OFF_CSRW     8519936u          // float[4][E]
#define OFF_H1       9568512u          // float[N][H][B] 10.5MB  (transposed layout)
#define OFF_XV       20054272u         // float[N][H][B]
#define OFF_Y        30540032u         // float[N][H][B]
#define OFF_H2       41025792u         // float[N][C][B]
#define OFF_YV       44695808u         // float[N][C][B]
#define OFF_T        OFF_H1            // float[N][40][B] 21MB, overlays H1+XV (dead by then)

// ---------------- CSR build ----------------
__global__ __launch_bounds__(256) void count_deg_kernel(
    const int* __restrict__ c0, const int* __restrict__ c1,
    const int* __restrict__ c2, const int* __restrict__ c3, int* __restrict__ deg)
{
    int idx = blockIdx.x * 256 + threadIdx.x;          // 4*E threads
    int g = idx >> 16, e = idx & 0xFFFF;
    const int* cp = g == 0 ? c0 : g == 1 ? c1 : g == 2 ? c2 : c3;
    atomicAdd(&deg[(g << 11) + cp[e]], 1);
}

__global__ __launch_bounds__(256) void scan_dinv_kernel(
    const int* __restrict__ deg, int* __restrict__ rowptr, float* __restrict__ dinv)
{
    int g = blockIdx.x, t = threadIdx.x;
    __shared__ int part[256];
    const int* d = deg + g * NN;
    int loc[8]; int s = 0;
#pragma unroll
    for (int j = 0; j < 8; ++j) { loc[j] = d[t * 8 + j]; s += loc[j]; }
    part[t] = s; __syncthreads();
    for (int off = 1; off < 256; off <<= 1) {
        int v = (t >= off) ? part[t - off] : 0;
        __syncthreads();
        part[t] += v;
        __syncthreads();
    }
    int run = (t > 0) ? part[t - 1] : 0;
    int* rp = rowptr + g * (NN + 1);
#pragma unroll
    for (int j = 0; j < 8; ++j) {
        int n = t * 8 + j;
        rp[n] = run; run += loc[j];
        dinv[g * NN + n] = loc[j] > 0 ? 1.0f / sqrtf((float)loc[j]) : 0.0f;
    }
    if (t == 255) rp[NN] = run;
}

__global__ __launch_bounds__(256) void fill_csr_kernel(
    const int* __restrict__ r0, const int* __restrict__ c0,
    const int* __restrict__ r1, const int* __restrict__ c1,
    const int* __restrict__ r2, const int* __restrict__ c2,
    const int* __restrict__ r3, const int* __restrict__ c3,
    const int* __restrict__ rowptr, int* __restrict__ cursor,
    const float* __restrict__ dinv, int* __restrict__ csrc, float* __restrict__ cw)
{
    int idx = blockIdx.x * 256 + threadIdx.x;
    int g = idx >> 16, e = idx & 0xFFFF;
    const int* rp = g == 0 ? r0 : g == 1 ? r1 : g == 2 ? r2 : r3;
    const int* cp = g == 0 ? c0 : g == 1 ? c1 : g == 2 ? c2 : c3;
    int r = rp[e], c = cp[e];
    int pos = atomicAdd(&cursor[(g << 11) + c], 1);
    int o = rowptr[g * (NN + 1) + c] + pos;
    csrc[(g << 16) + o] = r;
    cw[(g << 16) + o] = dinv[(g << 11) + r] * dinv[(g << 11) + c];
}

// ---------------- dual GEMM: [M,48] @ [48,20] x2, out in [n][k][b] layout ----------------
// Block = 256 threads = 4 nodes x 64 batch. Wave w handles k-group [5w,5w+5).
__global__ __launch_bounds__(256) void gemm48_dual(
    const float* __restrict__ X,
    const float* __restrict__ Wa, const float* __restrict__ Wb, int wstride,
    const float* __restrict__ ba, const float* __restrict__ bb,
    float* __restrict__ outA, float* __restrict__ outB, int nstride)
{
    __shared__ float xs[256 * 49];
    __shared__ float was[48 * 20], wbs[48 * 20];
    __shared__ float bas[20], bbs[20];
    int t = threadIdx.x;
    size_t base = (size_t)blockIdx.x * 256 * 48;

    // stage X tile: 12288 floats as 3072 float4 global loads, scalar LDS writes
    {
        int fl = 4 * t;
        int r = fl / 48, f = fl % 48;
#pragma unroll
        for (int i = 0; i < 12; ++i) {
            float4 v = *reinterpret_cast<const float4*>(&X[base + (size_t)r * 48 + f]);
            float* p = &xs[r * 49 + f];
            p[0] = v.x; p[1] = v.y; p[2] = v.z; p[3] = v.w;
            r += 21; f += 16;
            if (f >= 48) { f -= 48; r += 1; }
        }
    }
    for (int i = t; i < 960; i += 256) {
        int wf = i / 20, wk = i - wf * 20;
        was[i] = Wa[wf * wstride + wk];
        wbs[i] = Wb[wf * wstride + wk];
    }
    if (t < 20) {
        bas[t] = ba ? ba[t] : 0.0f;
        bbs[t] = bb ? bb[t] : 0.0f;
    }
    __syncthreads();

    int lane = t & 63, w = t >> 6;
    int kb = w * 5;
    float accA[4][5] = {}; float accB[4][5] = {};
    for (int f = 0; f < 48; ++f) {
        float x0 = xs[(lane +   0) * 49 + f];
        float x1 = xs[(lane +  64) * 49 + f];
        float x2 = xs[(lane + 128) * 49 + f];
        float x3 = xs[(lane + 192) * 49 + f];
#pragma unroll
        for (int j = 0; j < 5; ++j) {
            float wa = was[f * 20 + kb + j];
            float wb = wbs[f * 20 + kb + j];
            accA[0][j] += x0 * wa; accA[1][j] += x1 * wa;
            accA[2][j] += x2 * wa; accA[3][j] += x3 * wa;
            accB[0][j] += x0 * wb; accB[1][j] += x1 * wb;
            accB[2][j] += x2 * wb; accB[3][j] += x3 * wb;
        }
    }
    int node0 = blockIdx.x * 4;
#pragma unroll
    for (int i = 0; i < 4; ++i) {
        size_t ob = (size_t)(node0 + i) * nstride + lane;
#pragma unroll
        for (int j = 0; j < 5; ++j) {
            outA[ob + (size_t)(kb + j) * 64] = accA[i][j] + bas[kb + j];
            outB[ob + (size_t)(kb + j) * 64] = accB[i][j] + bbs[kb + j];
        }
    }
}

__device__ __forceinline__ void fma4(float4& a, float w, const float4 v) {
    a.x += w * v.x; a.y += w * v.y; a.z += w * v.z; a.w += w * v.w;
}
__device__ __forceinline__ float gelu_elu(float v) {
    float g = 0.5f * v * (1.0f + erff(v * 0.70710678118654752f));   // exact GELU
    return g > 0.0f ? g : expm1f(g);                                 // ELU
}

// ---------------- SpMM layer 1 + GELU + ELU (float4 gather, x4 unroll) ----------------
// Row = [H=20][B=64] = 320 float4. Chunk q = 64 float4 (4 h x 64 b) = one wave.
// grid = 5 chunks x 512 node-groups (chunk-major); block = 4 waves = 4 nodes.
__global__ __launch_bounds__(256) void spmm1_kernel(
    const float4* __restrict__ H1, const float4* __restrict__ XV, float4* __restrict__ Y,
    const int* __restrict__ rowptr, const int* __restrict__ src, const float* __restrict__ wts)
{
    int bx = blockIdx.x;
    int q = bx >> 9;                 // 0..4
    int ng = bx & 511;
    int w = threadIdx.x >> 6, lane = threadIdx.x & 63;
    int n = ng * 4 + w;
    int off = q * 64 + lane;         // float4 slot within the 320-slot row
    int s0 = rowptr[n], s1 = rowptr[n + 1];

    float4 a0 = {0,0,0,0}, a1 = {0,0,0,0}, a2 = {0,0,0,0}, a3 = {0,0,0,0};
    int e = s0;
    for (; e + 4 <= s1; e += 4) {
        int   sA = src[e],     sB = src[e + 1], sC = src[e + 2], sD = src[e + 3];
        float wA = wts[e],     wB = wts[e + 1], wC = wts[e + 2], wD = wts[e + 3];
        float4 vA = H1[sA * 320 + off];
        float4 vB = H1[sB * 320 + off];
        float4 vC = H1[sC * 320 + off];
        float4 vD = H1[sD * 320 + off];
        fma4(a0, wA, vA); fma4(a1, wB, vB); fma4(a2, wC, vC); fma4(a3, wD, vD);
    }
    for (; e < s1; ++e) fma4(a0, wts[e], H1[src[e] * 320 + off]);
    a0.x += a1.x + a2.x + a3.x;
    a0.y += a1.y + a2.y + a3.y;
    a0.z += a1.z + a2.z + a3.z;
    a0.w += a1.w + a2.w + a3.w;

    size_t b0 = (size_t)n * 320 + off;
    float4 xv = XV[b0];
    float4 r;
    r.x = gelu_elu(a0.x + xv.x);
    r.y = gelu_elu(a0.y + xv.y);
    r.z = gelu_elu(a0.z + xv.z);
    r.w = gelu_elu(a0.w + xv.w);
    Y[b0] = r;
}

// ---------------- dual GEMM 2: [M,20] @ [20,7] x2; Y in [n][h][b], out [n][c][b] ----------------
__global__ __launch_bounds__(256) void gemm2_dual(
    const float* __restrict__ Y, const float* __restrict__ W2,
    const float* __restrict__ V2, const float* __restrict__ b2,
    float* __restrict__ H2, float* __restrict__ YV)
{
    __shared__ float w2s[140], v2s[140], b2s[7];
    int t = threadIdx.x;
    if (t < 140) { w2s[t] = W2[t]; v2s[t] = V2[t]; }
    if (t < 7) b2s[t] = b2[t];
    __syncthreads();
    int wv = t >> 6, b = t & 63;
    int n = blockIdx.x * 4 + wv;
    size_t yb = (size_t)n * 1280 + b;
    float y[20];
#pragma unroll
    for (int k = 0; k < 20; ++k) y[k] = Y[yb + (size_t)k * 64];
    float a[7] = {}, v[7] = {};
#pragma unroll
    for (int k = 0; k < 20; ++k) {
        float yk = y[k];
#pragma unroll
        for (int c = 0; c < 7; ++c) {
            a[c] += yk * w2s[k * 7 + c];
            v[c] += yk * v2s[k * 7 + c];
        }
    }
    size_t hb = (size_t)n * 448 + b;
#pragma unroll
    for (int c = 0; c < 7; ++c) {
        H2[hb + (size_t)c * 64] = a[c];
        YV[hb + (size_t)c * 64] = v[c] + b2s[c];
    }
}

// ---------------- wave softmax over 64 lanes (batch axis) ----------------
__device__ __forceinline__ void wave_softmax7(float* z)
{
#pragma unroll
    for (int c = 0; c < 7; ++c) {
        float m = z[c];
#pragma unroll
        for (int o = 32; o > 0; o >>= 1) m = fmaxf(m, __shfl_xor(m, o, 64));
        float p = expf(z[c] - m);
        float s = p;
#pragma unroll
        for (int o = 32; o > 0; o >>= 1) s += __shfl_xor(s, o, 64);
        z[c] = p / s;
    }
}

// ---------------- SpMM layer 2 + ReLU + softmax(B) + accumulate; [n][c][b] ----------------
__global__ __launch_bounds__(256) void spmm2_kernel(
    const float* __restrict__ H2, const float* __restrict__ YV,
    const int* __restrict__ rowptr, const int* __restrict__ src, const float* __restrict__ wts,
    float* __restrict__ S, float coef)
{
    int wv = threadIdx.x >> 6, b = threadIdx.x & 63;
    int n = blockIdx.x * 4 + wv;
    int s0 = rowptr[n], s1 = rowptr[n + 1];
    float acc[7] = {};
    int e = s0;
    for (; e + 2 <= s1; e += 2) {
        int   sA = src[e],  sB = src[e + 1];
        float wA = wts[e],  wB = wts[e + 1];
        const float* hA = H2 + (size_t)sA * 448 + b;
        const float* hB = H2 + (size_t)sB * 448 + b;
#pragma unroll
        for (int c = 0; c < 7; ++c)
            acc[c] += wA * hA[c * 64] + wB * hB[c * 64];
    }
    for (; e < s1; ++e) {
        const float* hp = H2 + (size_t)src[e] * 448 + b;
        float w = wts[e];
#pragma unroll
        for (int c = 0; c < 7; ++c) acc[c] += w * hp[c * 64];
    }
    size_t base = (size_t)n * 448 + b;
    float z[7];
#pragma unroll
    for (int c = 0; c < 7; ++c) {
        float v = acc[c] + YV[base + (size_t)c * 64];
        z[c] = v > 0.0f ? v : 0.0f;
    }
    wave_softmax7(z);
#pragma unroll
    for (int c = 0; c < 7; ++c) S[base + (size_t)c * 64] += coef * z[c];
}

// ---------------- final: o_lt tail, dense+gnn heads, output [N][C][B] ----------------
__global__ __launch_bounds__(256) void combine_kernel(
    const float* __restrict__ T, const float* __restrict__ Sd, const float* __restrict__ Sg,
    const float* __restrict__ Wl2, const float* __restrict__ bl2,
    const float* __restrict__ Wd, const float* __restrict__ bd,
    const float* __restrict__ Wg, const float* __restrict__ bg,
    float* __restrict__ out)
{
    __shared__ float wl2s[280], bl2s[7], wds[49], bds[7], wgs[49], bgs[7];
    int t = threadIdx.x;
    for (int i = t; i < 280; i += 256) wl2s[i] = Wl2[i];
    if (t < 49) { wds[t] = Wd[t]; wgs[t] = Wg[t]; }
    if (t < 7) { bl2s[t] = bl2[t]; bds[t] = bd[t]; bgs[t] = bg[t]; }
    __syncthreads();

    int wv = t >> 6, b = t & 63;
    int n = blockIdx.x * 4 + wv;
    size_t rbase = (size_t)n * 2560 + b;   // T is [n][40][b]
    float tr[40];
#pragma unroll
    for (int j = 0; j < 40; ++j) tr[j] = T[rbase + (size_t)j * 64];

    float u[7];
#pragma unroll
    for (int c = 0; c < 7; ++c) u[c] = bl2s[c];
    for (int j = 0; j < 40; ++j) {
        float tv = tr[j];
#pragma unroll
        for (int c = 0; c < 7; ++c) u[c] += tv * wl2s[j * 7 + c];
    }
    wave_softmax7(u);   // o_lt

    size_t sbase = (size_t)n * 448 + b;
    float sd[7], dv[7];
#pragma unroll
    for (int c = 0; c < 7; ++c) sd[c] = Sd[sbase + (size_t)c * 64] + 2.0f * u[c];
#pragma unroll
    for (int c = 0; c < 7; ++c) dv[c] = bds[c];
#pragma unroll
    for (int c2 = 0; c2 < 7; ++c2) {
        float s = sd[c2];
#pragma unroll
        for (int c = 0; c < 7; ++c) dv[c] += s * wds[c2 * 7 + c];
    }
    wave_softmax7(dv);  // out_dense

    float sg[7], gv[7];
#pragma unroll
    for (int c = 0; c < 7; ++c) sg[c] = Sg[sbase + (size_t)c * 64];
#pragma unroll
    for (int c = 0; c < 7; ++c) gv[c] = bgs[c];
#pragma unroll
    for (int c2 = 0; c2 < 7; ++c2) {
        float s = sg[c2];
#pragma unroll
        for (int c = 0; c < 7; ++c) gv[c] += s * wgs[c2 * 7 + c];
    }
    wave_softmax7(gv);  // out_gnn

    size_t ob = (size_t)n * 448 + b;
#pragma unroll
    for (int c = 0; c < 7; ++c) out[ob + (size_t)c * 64] = dv[c] + gv[c];
}

// ---------------- host ----------------
extern "C" void kernel_launch(void* const* d_in, const int* in_sizes, int n_in,
                              void* d_out, int out_size, void* d_ws, size_t ws_size,
                              hipStream_t stream)
{
    (void)in_sizes; (void)n_in; (void)out_size; (void)ws_size;
    const int* e0 = (const int*)d_in[0];
    const int* e1 = (const int*)d_in[1];
    const int* e2 = (const int*)d_in[2];
    const int* e3 = (const int*)d_in[3];
    const float* Xin[6] = {
        (const float*)d_in[4], (const float*)d_in[5], (const float*)d_in[6],
        (const float*)d_in[7], (const float*)d_in[8], (const float*)d_in[9] };
    const float* W1  = (const float*)d_in[10];
    const float* V1  = (const float*)d_in[11];
    const float* b1  = (const float*)d_in[12];
    const float* W2  = (const float*)d_in[13];
    const float* V2  = (const float*)d_in[14];
    const float* b2  = (const float*)d_in[15];
    const float* Wlt = (const float*)d_in[16];
    const float* blt = (const float*)d_in[17];
    const float* Wl2 = (const float*)d_in[18];
    const float* bl2 = (const float*)d_in[19];
    const float* Wd  = (const float*)d_in[20];
    const float* bd  = (const float*)d_in[21];
    const float* Wg  = (const float*)d_in[22];
    const float* bg  = (const float*)d_in[23];

    char* ws = (char*)d_ws;
    int*   deg    = (int*)(ws + OFF_DEG);
    int*   cursor = (int*)(ws + OFF_CURSOR);
    float* Sgnn   = (float*)(ws + OFF_SGNN);
    float* Sdense = (float*)(ws + OFF_SDENSE);
    float* dinv   = (float*)(ws + OFF_DINV);
    int*   rowptr = (int*)(ws + OFF_ROWPTR);
    int*   csrc   = (int*)(ws + OFF_CSRC);
    float* csrw   = (float*)(ws + OFF_CSRW);
    float* H1     = (float*)(ws + OFF_H1);
    float* XV     = (float*)(ws + OFF_XV);
    float* Y      = (float*)(ws + OFF_Y);
    float* H2     = (float*)(ws + OFF_H2);
    float* YV     = (float*)(ws + OFF_YV);
    float* Tbuf   = (float*)(ws + OFF_T);

    hipMemsetAsync(d_ws, 0, ZBYTES, stream);

    count_deg_kernel<<<1024, 256, 0, stream>>>(e0 + EE, e1 + EE, e2 + EE, e3 + EE, deg);
    scan_dinv_kernel<<<4, 256, 0, stream>>>(deg, rowptr, dinv);
    fill_csr_kernel<<<1024, 256, 0, stream>>>(e0, e0 + EE, e1, e1 + EE, e2, e2 + EE,
                                              e3, e3 + EE, rowptr, cursor, dinv, csrc, csrw);

    const int GOF[6] = { 0, 1, 2, 0, 0, 3 };
    for (int i = 0; i < 6; ++i) {
        int g = GOF[i];
        const int*   rp = rowptr + g * (NN + 1);
        const int*   sc = csrc + (size_t)g * EE;
        const float* cw = csrw + (size_t)g * EE;
        gemm48_dual<<<512, 256, 0, stream>>>(Xin[i], W1 + i * 960, V1 + i * 960, 20,
                                             nullptr, b1 + i * 20, H1, XV, 1280);
        spmm1_kernel<<<2560, 256, 0, stream>>>((const float4*)H1, (const float4*)XV,
                                               (float4*)Y, rp, sc, cw);
        gemm2_dual<<<512, 256, 0, stream>>>(Y, W2 + i * 140, V2 + i * 140, b2 + i * 7, H2, YV);
        spmm2_kernel<<<512, 256, 0, stream>>>(H2, YV, rp, sc, cw,
                                              i < 5 ? Sgnn : Sdense, i < 5 ? 1.0f : 2.0f);
    }
    // o_lt linear part: T = Xlt@Wlt + blt, stored [n][40][b] (two 20-wide halves)
    gemm48_dual<<<512, 256, 0, stream>>>(Xin[5], Wlt, Wlt + 20, 40,
                                         blt, blt + 20, Tbuf, Tbuf + 20 * 64, 2560);
    combine_kernel<<<512, 256, 0, stream>>>(Tbuf, Sdense, Sgnn, Wl2, bl2, Wd, bd, Wg, bg,
                                            (float*)d_out);
}

// Round 3
// 399.779 us; speedup vs baseline: 1.6169x; 1.2668x over previous
//
#include <hip/hip_runtime.h>
#include <math.h>

// Problem dims
#define NN   2048      // nodes
#define BB   64        // batch
#define FF   48        // in features
#define EE   65536     // edges per graph
#define CC   7         // out channels
#define HH   20        // hidden

// ---- ws layout (bytes), ws_size = 256 MiB ----
// zero region (memset each call): deg[4][N] int, cursor[4][N] int
#define OFF_DEG      0u
#define OFF_CURSOR   32768u
#define ZBYTES       65536u
#define OFF_DINV     65536u            // float[4][N]
#define OFF_ROWPTR   98304u            // int[4][N+1]
#define OFF_CSRC     131584u           // int[4][E]
#define OFF_CSRW     1180160u          // float[4][E]
#define OFF_H1       2228736u          // 6 x float[N][20][B] = 6 x 10.49MB
#define OFF_P        OFF_H1            // 6 x float[N][7][B], overlays H1 (dead at spmm2)
#define OFF_Y        65143296u         // 6 x float[N][20][B]; init = xV+b, then act in place
#define OFF_H2       128057856u        // 6 x float[N][8][B] (padded to 8 ch) = 6 x 4MB
#define OFF_YV       153223680u        // 6 x float[N][7][B]
#define OFF_T        175243776u        // float[N][40][B] 21MB
// end = 196,215,296 B < 256 MiB

#define H1S  2621440u   // floats per branch in H1/Y
#define H2S  1048576u   // floats per branch in H2 (padded)
#define YVS  917504u    // floats per branch in YV / P

// ---------------- CSR build ----------------
__global__ __launch_bounds__(256) void count_deg_kernel(
    const int* __restrict__ c0, const int* __restrict__ c1,
    const int* __restrict__ c2, const int* __restrict__ c3, int* __restrict__ deg)
{
    int idx = blockIdx.x * 256 + threadIdx.x;          // 4*E threads
    int g = idx >> 16, e = idx & 0xFFFF;
    const int* cp = g == 0 ? c0 : g == 1 ? c1 : g == 2 ? c2 : c3;
    atomicAdd(&deg[(g << 11) + cp[e]], 1);
}

__global__ __launch_bounds__(256) void scan_dinv_kernel(
    const int* __restrict__ deg, int* __restrict__ rowptr, float* __restrict__ dinv)
{
    int g = blockIdx.x, t = threadIdx.x;
    __shared__ int part[256];
    const int* d = deg + g * NN;
    int loc[8]; int s = 0;
#pragma unroll
    for (int j = 0; j < 8; ++j) { loc[j] = d[t * 8 + j]; s += loc[j]; }
    part[t] = s; __syncthreads();
    for (int off = 1; off < 256; off <<= 1) {
        int v = (t >= off) ? part[t - off] : 0;
        __syncthreads();
        part[t] += v;
        __syncthreads();
    }
    int run = (t > 0) ? part[t - 1] : 0;
    int* rp = rowptr + g * (NN + 1);
#pragma unroll
    for (int j = 0; j < 8; ++j) {
        int n = t * 8 + j;
        rp[n] = run; run += loc[j];
        dinv[g * NN + n] = loc[j] > 0 ? 1.0f / sqrtf((float)loc[j]) : 0.0f;
    }
    if (t == 255) rp[NN] = run;
}

__global__ __launch_bounds__(256) void fill_csr_kernel(
    const int* __restrict__ r0, const int* __restrict__ c0,
    const int* __restrict__ r1, const int* __restrict__ c1,
    const int* __restrict__ r2, const int* __restrict__ c2,
    const int* __restrict__ r3, const int* __restrict__ c3,
    const int* __restrict__ rowptr, int* __restrict__ cursor,
    const float* __restrict__ dinv, int* __restrict__ csrc, float* __restrict__ cw)
{
    int idx = blockIdx.x * 256 + threadIdx.x;
    int g = idx >> 16, e = idx & 0xFFFF;
    const int* rp = g == 0 ? r0 : g == 1 ? r1 : g == 2 ? r2 : r3;
    const int* cp = g == 0 ? c0 : g == 1 ? c1 : g == 2 ? c2 : c3;
    int r = rp[e], c = cp[e];
    int pos = atomicAdd(&cursor[(g << 11) + c], 1);
    int o = rowptr[g * (NN + 1) + c] + pos;
    csrc[(g << 16) + o] = r;
    cw[(g << 16) + o] = dinv[(g << 11) + r] * dinv[(g << 11) + c];
}

// ---------------- batched dual GEMM: [M,48] @ [48,20] x2, out [n][k][b] ----------------
// grid = (512 tiles, 7 branches); branch 6 computes T = Xlt@Wlt+blt (two 20-col halves).
__global__ __launch_bounds__(256) void gemm48_all(
    const float* __restrict__ X0, const float* __restrict__ X1,
    const float* __restrict__ X2, const float* __restrict__ X3,
    const float* __restrict__ X4, const float* __restrict__ X5,
    const float* __restrict__ W1, const float* __restrict__ V1, const float* __restrict__ b1,
    const float* __restrict__ Wlt, const float* __restrict__ blt,
    float* __restrict__ H1, float* __restrict__ Y, float* __restrict__ T)
{
    int br = blockIdx.y;
    const float* X; const float* Wa; const float* Wb; const float* ba; const float* bb;
    float* outA; float* outB; int wstride, nstride;
    if (br < 6) {
        X = br == 0 ? X0 : br == 1 ? X1 : br == 2 ? X2 : br == 3 ? X3 : br == 4 ? X4 : X5;
        Wa = W1 + br * 960; Wb = V1 + br * 960; wstride = 20;
        ba = nullptr; bb = b1 + br * 20;
        outA = H1 + (size_t)br * H1S; outB = Y + (size_t)br * H1S; nstride = 1280;
    } else {
        X = X5; Wa = Wlt; Wb = Wlt + 20; wstride = 40;
        ba = blt; bb = blt + 20;
        outA = T; outB = T + 1280; nstride = 2560;
    }

    __shared__ float xs[256 * 49];
    __shared__ float was[48 * 20], wbs[48 * 20];
    __shared__ float bas[20], bbs[20];
    int t = threadIdx.x;
    size_t base = (size_t)blockIdx.x * 256 * 48;

    {
        int fl = 4 * t;
        int r = fl / 48, f = fl % 48;
#pragma unroll
        for (int i = 0; i < 12; ++i) {
            float4 v = *reinterpret_cast<const float4*>(&X[base + (size_t)r * 48 + f]);
            float* p = &xs[r * 49 + f];
            p[0] = v.x; p[1] = v.y; p[2] = v.z; p[3] = v.w;
            r += 21; f += 16;
            if (f >= 48) { f -= 48; r += 1; }
        }
    }
    for (int i = t; i < 960; i += 256) {
        int wf = i / 20, wk = i - wf * 20;
        was[i] = Wa[wf * wstride + wk];
        wbs[i] = Wb[wf * wstride + wk];
    }
    if (t < 20) {
        bas[t] = ba ? ba[t] : 0.0f;
        bbs[t] = bb ? bb[t] : 0.0f;
    }
    __syncthreads();

    int lane = t & 63, w = t >> 6;
    int kb = w * 5;
    float accA[4][5] = {}; float accB[4][5] = {};
    for (int f = 0; f < 48; ++f) {
        float x0 = xs[(lane +   0) * 49 + f];
        float x1 = xs[(lane +  64) * 49 + f];
        float x2 = xs[(lane + 128) * 49 + f];
        float x3 = xs[(lane + 192) * 49 + f];
#pragma unroll
        for (int j = 0; j < 5; ++j) {
            float wa = was[f * 20 + kb + j];
            float wb = wbs[f * 20 + kb + j];
            accA[0][j] += x0 * wa; accA[1][j] += x1 * wa;
            accA[2][j] += x2 * wa; accA[3][j] += x3 * wa;
            accB[0][j] += x0 * wb; accB[1][j] += x1 * wb;
            accB[2][j] += x2 * wb; accB[3][j] += x3 * wb;
        }
    }
    int node0 = blockIdx.x * 4;
#pragma unroll
    for (int i = 0; i < 4; ++i) {
        size_t ob = (size_t)(node0 + i) * nstride + lane;
#pragma unroll
        for (int j = 0; j < 5; ++j) {
            outA[ob + (size_t)(kb + j) * 64] = accA[i][j] + bas[kb + j];
            outB[ob + (size_t)(kb + j) * 64] = accB[i][j] + bbs[kb + j];
        }
    }
}

__device__ __forceinline__ void fma4(float4& a, float w, const float4 v) {
    a.x += w * v.x; a.y += w * v.y; a.z += w * v.z; a.w += w * v.w;
}
__device__ __forceinline__ float gelu_elu(float v) {
    float g = 0.5f * v * (1.0f + erff(v * 0.70710678118654752f));   // exact GELU
    return g > 0.0f ? g : expm1f(g);                                 // ELU
}

// ---------------- batched SpMM1 + GELU + ELU, in-place on Y (= xV+b) ----------------
// grid = (5 chunks x 512 groups, 6 branches); block = 4 waves = 4 nodes.
__global__ __launch_bounds__(256) void spmm1_all(
    const float4* __restrict__ H1, float4* __restrict__ Y,
    const int* __restrict__ rowptr, const int* __restrict__ csrc, const float* __restrict__ csrw)
{
    int br = blockIdx.y;
    int g = br == 1 ? 1 : br == 2 ? 2 : br == 5 ? 3 : 0;
    const int*   rp  = rowptr + g * (NN + 1);
    const int*   src = csrc + (size_t)g * EE;
    const float* wts = csrw + (size_t)g * EE;
    const float4* h = H1 + (size_t)br * (H1S / 4);
    float4*       y = Y  + (size_t)br * (H1S / 4);

    int q = blockIdx.x >> 9;         // 0..4
    int ng = blockIdx.x & 511;
    int w = threadIdx.x >> 6, lane = threadIdx.x & 63;
    int n = ng * 4 + w;
    int off = q * 64 + lane;         // float4 slot within the 320-slot row
    int s0 = rp[n], s1 = rp[n + 1];

    float4 a0 = {0,0,0,0}, a1 = {0,0,0,0}, a2 = {0,0,0,0}, a3 = {0,0,0,0};
    int e = s0;
    for (; e + 4 <= s1; e += 4) {
        int   sA = src[e],     sB = src[e + 1], sC = src[e + 2], sD = src[e + 3];
        float wA = wts[e],     wB = wts[e + 1], wC = wts[e + 2], wD = wts[e + 3];
        float4 vA = h[sA * 320 + off];
        float4 vB = h[sB * 320 + off];
        float4 vC = h[sC * 320 + off];
        float4 vD = h[sD * 320 + off];
        fma4(a0, wA, vA); fma4(a1, wB, vB); fma4(a2, wC, vC); fma4(a3, wD, vD);
    }
    for (; e < s1; ++e) fma4(a0, wts[e], h[src[e] * 320 + off]);
    a0.x += a1.x + a2.x + a3.x;
    a0.y += a1.y + a2.y + a3.y;
    a0.z += a1.z + a2.z + a3.z;
    a0.w += a1.w + a2.w + a3.w;

    size_t b0 = (size_t)n * 320 + off;
    float4 xv = y[b0];
    float4 r;
    r.x = gelu_elu(a0.x + xv.x);
    r.y = gelu_elu(a0.y + xv.y);
    r.z = gelu_elu(a0.z + xv.z);
    r.w = gelu_elu(a0.w + xv.w);
    y[b0] = r;
}

// ---------------- batched dual GEMM2: [M,20]@[20,7] x2; H2 padded to 8 ch ----------------
// grid = (512, 6); block = 4 waves = 4 nodes.
__global__ __launch_bounds__(256) void gemm2_all(
    const float* __restrict__ Y, const float* __restrict__ W2,
    const float* __restrict__ V2, const float* __restrict__ b2,
    float* __restrict__ H2, float* __restrict__ YV)
{
    int br = blockIdx.y;
    const float* y  = Y + (size_t)br * H1S;
    float* h2 = H2 + (size_t)br * H2S;
    float* yv = YV + (size_t)br * YVS;
    __shared__ float w2s[140], v2s[140], b2s[7];
    int t = threadIdx.x;
    if (t < 140) { w2s[t] = W2[br * 140 + t]; v2s[t] = V2[br * 140 + t]; }
    if (t < 7) b2s[t] = b2[br * 7 + t];
    __syncthreads();
    int wv = t >> 6, b = t & 63;
    int n = blockIdx.x * 4 + wv;
    size_t yb = (size_t)n * 1280 + b;
    float yr[20];
#pragma unroll
    for (int k = 0; k < 20; ++k) yr[k] = y[yb + (size_t)k * 64];
    float a[7] = {}, v[7] = {};
#pragma unroll
    for (int k = 0; k < 20; ++k) {
        float yk = yr[k];
#pragma unroll
        for (int c = 0; c < 7; ++c) {
            a[c] += yk * w2s[k * 7 + c];
            v[c] += yk * v2s[k * 7 + c];
        }
    }
    size_t hb = (size_t)n * 512 + b;
#pragma unroll
    for (int c = 0; c < 7; ++c) h2[hb + (size_t)c * 64] = a[c];
    h2[hb + 7 * 64] = 0.0f;                       // padding channel
    size_t vb = (size_t)n * 448 + b;
#pragma unroll
    for (int c = 0; c < 7; ++c) yv[vb + (size_t)c * 64] = v[c] + b2s[c];
}

// ---------------- batched SpMM2 + ReLU + softmax(B) -> per-branch P ----------------
// grid = (2 halves x 512 groups, 6 branches); block = 4 waves = 4 nodes (one half each).
// Row = [8 ch][64 b] = 128 float4; wave handles 64 slots: c = slot>>4, b = (slot&15)*4+j.
__global__ __launch_bounds__(256) void spmm2_all(
    const float4* __restrict__ H2, const float* __restrict__ YV,
    const int* __restrict__ rowptr, const int* __restrict__ csrc, const float* __restrict__ csrw,
    float* __restrict__ P)
{
    int br = blockIdx.y;
    int g = br == 1 ? 1 : br == 2 ? 2 : br == 5 ? 3 : 0;
    const int*   rp  = rowptr + g * (NN + 1);
    const int*   src = csrc + (size_t)g * EE;
    const float* wts = csrw + (size_t)g * EE;
    const float4* h2 = H2 + (size_t)br * (H2S / 4);
    const float* yv = YV + (size_t)br * YVS;
    float* p = P + (size_t)br * YVS;

    int hh = blockIdx.x >> 9, ng = blockIdx.x & 511;
    int w = threadIdx.x >> 6, lane = threadIdx.x & 63;
    int n = ng * 4 + w;
    int s = hh * 64 + lane;          // float4 slot in the 128-slot row
    int c = s >> 4;                  // 0..7 (7 = padding)
    int bq = lane & 15;              // b quad
    int s0 = rp[n], s1 = rp[n + 1];

    float4 a0 = {0,0,0,0}, a1 = {0,0,0,0}, a2 = {0,0,0,0}, a3 = {0,0,0,0};
    int e = s0;
    for (; e + 4 <= s1; e += 4) {
        int   sA = src[e],     sB = src[e + 1], sC = src[e + 2], sD = src[e + 3];
        float wA = wts[e],     wB = wts[e + 1], wC = wts[e + 2], wD = wts[e + 3];
        float4 vA = h2[sA * 128 + s];
        float4 vB = h2[sB * 128 + s];
        float4 vC = h2[sC * 128 + s];
        float4 vD = h2[sD * 128 + s];
        fma4(a0, wA, vA); fma4(a1, wB, vB); fma4(a2, wC, vC); fma4(a3, wD, vD);
    }
    for (; e < s1; ++e) fma4(a0, wts[e], h2[src[e] * 128 + s]);
    a0.x += a1.x + a2.x + a3.x;
    a0.y += a1.y + a2.y + a3.y;
    a0.z += a1.z + a2.z + a3.z;
    a0.w += a1.w + a2.w + a3.w;

    float4 z = {0,0,0,0};
    if (c < 7) {
        float4 yvv = *reinterpret_cast<const float4*>(&yv[(size_t)n * 448 + c * 64 + bq * 4]);
        z.x = fmaxf(a0.x + yvv.x, 0.0f);
        z.y = fmaxf(a0.y + yvv.y, 0.0f);
        z.z = fmaxf(a0.z + yvv.z, 0.0f);
        z.w = fmaxf(a0.w + yvv.w, 0.0f);
    }
    // softmax over batch: 16 lanes (same c) x 4 components
    float m = fmaxf(fmaxf(z.x, z.y), fmaxf(z.z, z.w));
#pragma unroll
    for (int o = 8; o > 0; o >>= 1) m = fmaxf(m, __shfl_xor(m, o, 64));
    float4 pz;
    pz.x = expf(z.x - m); pz.y = expf(z.y - m);
    pz.z = expf(z.z - m); pz.w = expf(z.w - m);
    float sm = pz.x + pz.y + pz.z + pz.w;
#pragma unroll
    for (int o = 8; o > 0; o >>= 1) sm += __shfl_xor(sm, o, 64);
    float inv = 1.0f / sm;
    if (c < 7) {
        float4 r = { pz.x * inv, pz.y * inv, pz.z * inv, pz.w * inv };
        *reinterpret_cast<float4*>(&p[(size_t)n * 448 + c * 64 + bq * 4]) = r;
    }
}

// ---------------- wave softmax over 64 lanes (batch axis) ----------------
__device__ __forceinline__ void wave_softmax7(float* z)
{
#pragma unroll
    for (int c = 0; c < 7; ++c) {
        float m = z[c];
#pragma unroll
        for (int o = 32; o > 0; o >>= 1) m = fmaxf(m, __shfl_xor(m, o, 64));
        float p = expf(z[c] - m);
        float s = p;
#pragma unroll
        for (int o = 32; o > 0; o >>= 1) s += __shfl_xor(s, o, 64);
        z[c] = p / s;
    }
}

// ---------------- final: o_lt tail, dense+gnn heads, output [N][C][B] ----------------
__global__ __launch_bounds__(256) void combine_kernel(
    const float* __restrict__ T, const float* __restrict__ P,
    const float* __restrict__ Wl2, const float* __restrict__ bl2,
    const float* __restrict__ Wd, const float* __restrict__ bd,
    const float* __restrict__ Wg, const float* __restrict__ bg,
    float* __restrict__ out)
{
    __shared__ float wl2s[280], bl2s[7], wds[49], bds[7], wgs[49], bgs[7];
    int t = threadIdx.x;
    for (int i = t; i < 280; i += 256) wl2s[i] = Wl2[i];
    if (t < 49) { wds[t] = Wd[t]; wgs[t] = Wg[t]; }
    if (t < 7) { bl2s[t] = bl2[t]; bds[t] = bd[t]; bgs[t] = bg[t]; }
    __syncthreads();

    int wv = t >> 6, b = t & 63;
    int n = blockIdx.x * 4 + wv;
    size_t rbase = (size_t)n * 2560 + b;   // T is [n][40][b]
    float tr[40];
#pragma unroll
    for (int j = 0; j < 40; ++j) tr[j] = T[rbase + (size_t)j * 64];

    float u[7];
#pragma unroll
    for (int c = 0; c < 7; ++c) u[c] = bl2s[c];
    for (int j = 0; j < 40; ++j) {
        float tv = tr[j];
#pragma unroll
        for (int c = 0; c < 7; ++c) u[c] += tv * wl2s[j * 7 + c];
    }
    wave_softmax7(u);   // o_lt

    size_t sbase = (size_t)n * 448 + b;
    float sd[7], sg[7];
#pragma unroll
    for (int c = 0; c < 7; ++c) {
        size_t o = sbase + (size_t)c * 64;
        sg[c] = P[o] + P[YVS + o] + P[2 * YVS + o] + P[3 * YVS + o] + P[4 * YVS + o];
        sd[c] = 2.0f * P[5 * YVS + o] + 2.0f * u[c];
    }
    float dv[7];
#pragma unroll
    for (int c = 0; c < 7; ++c) dv[c] = bds[c];
#pragma unroll
    for (int c2 = 0; c2 < 7; ++c2) {
        float s = sd[c2];
#pragma unroll
        for (int c = 0; c < 7; ++c) dv[c] += s * wds[c2 * 7 + c];
    }
    wave_softmax7(dv);  // out_dense

    float gv[7];
#pragma unroll
    for (int c = 0; c < 7; ++c) gv[c] = bgs[c];
#pragma unroll
    for (int c2 = 0; c2 < 7; ++c2) {
        float s = sg[c2];
#pragma unroll
        for (int c = 0; c < 7; ++c) gv[c] += s * wgs[c2 * 7 + c];
    }
    wave_softmax7(gv);  // out_gnn

    size_t ob = (size_t)n * 448 + b;
#pragma unroll
    for (int c = 0; c < 7; ++c) out[ob + (size_t)c * 64] = dv[c] + gv[c];
}

// ---------------- host ----------------
extern "C" void kernel_launch(void* const* d_in, const int* in_sizes, int n_in,
                              void* d_out, int out_size, void* d_ws, size_t ws_size,
                              hipStream_t stream)
{
    (void)in_sizes; (void)n_in; (void)out_size; (void)ws_size;
    const int* e0 = (const int*)d_in[0];
    const int* e1 = (const int*)d_in[1];
    const int* e2 = (const int*)d_in[2];
    const int* e3 = (const int*)d_in[3];
    const float* X0 = (const float*)d_in[4];
    const float* X1 = (const float*)d_in[5];
    const float* X2 = (const float*)d_in[6];
    const float* X3 = (const float*)d_in[7];
    const float* X4 = (const float*)d_in[8];
    const float* X5 = (const float*)d_in[9];
    const float* W1  = (const float*)d_in[10];
    const float* V1  = (const float*)d_in[11];
    const float* b1  = (const float*)d_in[12];
    const float* W2  = (const float*)d_in[13];
    const float* V2  = (const float*)d_in[14];
    const float* b2  = (const float*)d_in[15];
    const float* Wlt = (const float*)d_in[16];
    const float* blt = (const float*)d_in[17];
    const float* Wl2 = (const float*)d_in[18];
    const float* bl2 = (const float*)d_in[19];
    const float* Wd  = (const float*)d_in[20];
    const float* bd  = (const float*)d_in[21];
    const float* Wg  = (const float*)d_in[22];
    const float* bg  = (const float*)d_in[23];

    char* ws = (char*)d_ws;
    int*   deg    = (int*)(ws + OFF_DEG);
    int*   cursor = (int*)(ws + OFF_CURSOR);
    float* dinv   = (float*)(ws + OFF_DINV);
    int*   rowptr = (int*)(ws + OFF_ROWPTR);
    int*   csrc   = (int*)(ws + OFF_CSRC);
    float* csrw   = (float*)(ws + OFF_CSRW);
    float* H1     = (float*)(ws + OFF_H1);
    float* Pbuf   = (float*)(ws + OFF_P);
    float* Y      = (float*)(ws + OFF_Y);
    float* H2     = (float*)(ws + OFF_H2);
    float* YV     = (float*)(ws + OFF_YV);
    float* Tbuf   = (float*)(ws + OFF_T);

    hipMemsetAsync(d_ws, 0, ZBYTES, stream);

    count_deg_kernel<<<1024, 256, 0, stream>>>(e0 + EE, e1 + EE, e2 + EE, e3 + EE, deg);
    scan_dinv_kernel<<<4, 256, 0, stream>>>(deg, rowptr, dinv);
    fill_csr_kernel<<<1024, 256, 0, stream>>>(e0, e0 + EE, e1, e1 + EE, e2, e2 + EE,
                                              e3, e3 + EE, rowptr, cursor, dinv, csrc, csrw);

    gemm48_all<<<dim3(512, 7), 256, 0, stream>>>(X0, X1, X2, X3, X4, X5,
                                                 W1, V1, b1, Wlt, blt, H1, Y, Tbuf);
    spmm1_all<<<dim3(2560, 6), 256, 0, stream>>>((const float4*)H1, (float4*)Y,
                                                 rowptr, csrc, csrw);
    gemm2_all<<<dim3(512, 6), 256, 0, stream>>>(Y, W2, V2, b2, H2, YV);
    spmm2_all<<<dim3(1024, 6), 256, 0, stream>>>((const float4*)H2, YV,
                                                 rowptr, csrc, csrw, Pbuf);
    combine_kernel<<<512, 256, 0, stream>>>(Tbuf, Pbuf, Wl2, bl2, Wd, bd, Wg, bg,
                                            (float*)d_out);
}

// Round 4
// 330.605 us; speedup vs baseline: 1.9552x; 1.2092x over previous
//
#include <hip/hip_runtime.h>
#include <math.h>

// Problem dims
#define NN   2048      // nodes
#define BB   64        // batch
#define FF   48        // in features
#define EE   65536     // edges per graph
#define CC   7         // out channels
#define HH   20        // hidden

// ---- ws layout (bytes), ws_size = 256 MiB ----
#define OFF_DEG      0u
#define OFF_CURSOR   32768u
#define ZBYTES       65536u
#define OFF_DINV     65536u            // float[4][N]
#define OFF_ROWPTR   98304u            // int[4][N+1]
#define OFF_CSRC     131584u           // int[4][E]
#define OFF_CSRW     1180160u          // float[4][E]
#define OFF_H1       2228736u          // 6 x float[N][20][B] = 6 x 10.49MB
#define OFF_P        OFF_H1            // 6 x float[N][7][B], overlays H1 (dead at spmm2)
#define OFF_Y        65143296u         // 6 x float[N][20][B]; init = xV+b, then act in place
#define OFF_H2       128057856u        // 6 x float[N][8][B] (padded to 8 ch) = 6 x 4MB
#define OFF_YV       153223680u        // 6 x float[N][7][B]
#define OFF_T        175243776u        // float[N][40][B] 21MB
// end = 196,215,296 B < 256 MiB

#define H1S  2621440u   // floats per branch in H1/Y
#define H2S  1048576u   // floats per branch in H2 (padded)
#define YVS  917504u    // floats per branch in YV / P

// ---------------- CSR build ----------------
__global__ __launch_bounds__(256) void count_deg_kernel(
    const int* __restrict__ c0, const int* __restrict__ c1,
    const int* __restrict__ c2, const int* __restrict__ c3, int* __restrict__ deg)
{
    int idx = blockIdx.x * 256 + threadIdx.x;          // 4*E threads
    int g = idx >> 16, e = idx & 0xFFFF;
    const int* cp = g == 0 ? c0 : g == 1 ? c1 : g == 2 ? c2 : c3;
    atomicAdd(&deg[(g << 11) + cp[e]], 1);
}

__global__ __launch_bounds__(256) void scan_dinv_kernel(
    const int* __restrict__ deg, int* __restrict__ rowptr, float* __restrict__ dinv)
{
    int g = blockIdx.x, t = threadIdx.x;
    __shared__ int part[256];
    const int* d = deg + g * NN;
    int loc[8]; int s = 0;
#pragma unroll
    for (int j = 0; j < 8; ++j) { loc[j] = d[t * 8 + j]; s += loc[j]; }
    part[t] = s; __syncthreads();
    for (int off = 1; off < 256; off <<= 1) {
        int v = (t >= off) ? part[t - off] : 0;
        __syncthreads();
        part[t] += v;
        __syncthreads();
    }
    int run = (t > 0) ? part[t - 1] : 0;
    int* rp = rowptr + g * (NN + 1);
#pragma unroll
    for (int j = 0; j < 8; ++j) {
        int n = t * 8 + j;
        rp[n] = run; run += loc[j];
        dinv[g * NN + n] = loc[j] > 0 ? 1.0f / sqrtf((float)loc[j]) : 0.0f;
    }
    if (t == 255) rp[NN] = run;
}

__global__ __launch_bounds__(256) void fill_csr_kernel(
    const int* __restrict__ r0, const int* __restrict__ c0,
    const int* __restrict__ r1, const int* __restrict__ c1,
    const int* __restrict__ r2, const int* __restrict__ c2,
    const int* __restrict__ r3, const int* __restrict__ c3,
    const int* __restrict__ rowptr, int* __restrict__ cursor,
    const float* __restrict__ dinv, int* __restrict__ csrc, float* __restrict__ cw)
{
    int idx = blockIdx.x * 256 + threadIdx.x;
    int g = idx >> 16, e = idx & 0xFFFF;
    const int* rp = g == 0 ? r0 : g == 1 ? r1 : g == 2 ? r2 : r3;
    const int* cp = g == 0 ? c0 : g == 1 ? c1 : g == 2 ? c2 : c3;
    int r = rp[e], c = cp[e];
    int pos = atomicAdd(&cursor[(g << 11) + c], 1);
    int o = rowptr[g * (NN + 1) + c] + pos;
    csrc[(g << 16) + o] = r;
    cw[(g << 16) + o] = dinv[(g << 11) + r] * dinv[(g << 11) + c];
}

// ---------------- batched dual GEMM: [M,48] @ [48,20] x2, out [n][k][b] ----------------
// grid = (512 tiles, 7 branches); branch 6 computes T = Xlt@Wlt+blt (two 20-col halves).
__global__ __launch_bounds__(256) void gemm48_all(
    const float* __restrict__ X0, const float* __restrict__ X1,
    const float* __restrict__ X2, const float* __restrict__ X3,
    const float* __restrict__ X4, const float* __restrict__ X5,
    const float* __restrict__ W1, const float* __restrict__ V1, const float* __restrict__ b1,
    const float* __restrict__ Wlt, const float* __restrict__ blt,
    float* __restrict__ H1, float* __restrict__ Y, float* __restrict__ T)
{
    int br = blockIdx.y;
    const float* X; const float* Wa; const float* Wb; const float* ba; const float* bb;
    float* outA; float* outB; int wstride, nstride;
    if (br < 6) {
        X = br == 0 ? X0 : br == 1 ? X1 : br == 2 ? X2 : br == 3 ? X3 : br == 4 ? X4 : X5;
        Wa = W1 + br * 960; Wb = V1 + br * 960; wstride = 20;
        ba = nullptr; bb = b1 + br * 20;
        outA = H1 + (size_t)br * H1S; outB = Y + (size_t)br * H1S; nstride = 1280;
    } else {
        X = X5; Wa = Wlt; Wb = Wlt + 20; wstride = 40;
        ba = blt; bb = blt + 20;
        outA = T; outB = T + 1280; nstride = 2560;
    }

    __shared__ float xs[256 * 49];
    __shared__ float was[48 * 20], wbs[48 * 20];
    __shared__ float bas[20], bbs[20];
    int t = threadIdx.x;
    size_t base = (size_t)blockIdx.x * 256 * 48;

    {
        int fl = 4 * t;
        int r = fl / 48, f = fl % 48;
#pragma unroll
        for (int i = 0; i < 12; ++i) {
            float4 v = *reinterpret_cast<const float4*>(&X[base + (size_t)r * 48 + f]);
            float* p = &xs[r * 49 + f];
            p[0] = v.x; p[1] = v.y; p[2] = v.z; p[3] = v.w;
            r += 21; f += 16;
            if (f >= 48) { f -= 48; r += 1; }
        }
    }
    for (int i = t; i < 960; i += 256) {
        int wf = i / 20, wk = i - wf * 20;
        was[i] = Wa[wf * wstride + wk];
        wbs[i] = Wb[wf * wstride + wk];
    }
    if (t < 20) {
        bas[t] = ba ? ba[t] : 0.0f;
        bbs[t] = bb ? bb[t] : 0.0f;
    }
    __syncthreads();

    int lane = t & 63, w = t >> 6;
    int kb = w * 5;
    float accA[4][5] = {}; float accB[4][5] = {};
    for (int f = 0; f < 48; ++f) {
        float x0 = xs[(lane +   0) * 49 + f];
        float x1 = xs[(lane +  64) * 49 + f];
        float x2 = xs[(lane + 128) * 49 + f];
        float x3 = xs[(lane + 192) * 49 + f];
#pragma unroll
        for (int j = 0; j < 5; ++j) {
            float wa = was[f * 20 + kb + j];
            float wb = wbs[f * 20 + kb + j];
            accA[0][j] += x0 * wa; accA[1][j] += x1 * wa;
            accA[2][j] += x2 * wa; accA[3][j] += x3 * wa;
            accB[0][j] += x0 * wb; accB[1][j] += x1 * wb;
            accB[2][j] += x2 * wb; accB[3][j] += x3 * wb;
        }
    }
    int node0 = blockIdx.x * 4;
#pragma unroll
    for (int i = 0; i < 4; ++i) {
        size_t ob = (size_t)(node0 + i) * nstride + lane;
#pragma unroll
        for (int j = 0; j < 5; ++j) {
            outA[ob + (size_t)(kb + j) * 64] = accA[i][j] + bas[kb + j];
            outB[ob + (size_t)(kb + j) * 64] = accB[i][j] + bbs[kb + j];
        }
    }
}

__device__ __forceinline__ void fma4(float4& a, float w, const float4 v) {
    a.x += w * v.x; a.y += w * v.y; a.z += w * v.z; a.w += w * v.w;
}
__device__ __forceinline__ float gelu_elu(float v) {
    float g = 0.5f * v * (1.0f + erff(v * 0.70710678118654752f));   // exact GELU
    return g > 0.0f ? g : expm1f(g);                                 // ELU
}

// ---------------- batched SpMM1 + GELU + ELU, in-place on Y (= xV+b) ----------------
// XCD-pinned slices: 30 slices (br x chunk) of 512 node-groups; XCD x = bid&7 runs
// contiguous work slots w = x*1920 + (bid>>3), slice = w/512 (2.1MB, L2-resident).
__global__ __launch_bounds__(256) void spmm1_all(
    const float4* __restrict__ H1, float4* __restrict__ Y,
    const int* __restrict__ rowptr, const int* __restrict__ csrc, const float* __restrict__ csrw)
{
    int bid = blockIdx.x;
    int w0 = (bid & 7) * 1920 + (bid >> 3);   // 0..15359
    int sl = w0 >> 9;                          // 0..29
    int ng = w0 & 511;
    int br = sl / 5, q = sl - br * 5;

    int gg = br == 1 ? 1 : br == 2 ? 2 : br == 5 ? 3 : 0;
    const int*   rp  = rowptr + gg * (NN + 1);
    const int*   src = csrc + (size_t)gg * EE;
    const float* wts = csrw + (size_t)gg * EE;
    const float4* h = H1 + (size_t)br * (H1S / 4);
    float4*       y = Y  + (size_t)br * (H1S / 4);

    int w = threadIdx.x >> 6, lane = threadIdx.x & 63;
    int n = ng * 4 + w;
    int off = q * 64 + lane;         // float4 slot within the 320-slot row
    int s0 = rp[n], s1 = rp[n + 1];

    float4 a0 = {0,0,0,0}, a1 = {0,0,0,0}, a2 = {0,0,0,0}, a3 = {0,0,0,0};
    int e = s0;
    for (; e + 4 <= s1; e += 4) {
        int   sA = src[e],     sB = src[e + 1], sC = src[e + 2], sD = src[e + 3];
        float wA = wts[e],     wB = wts[e + 1], wC = wts[e + 2], wD = wts[e + 3];
        float4 vA = h[sA * 320 + off];
        float4 vB = h[sB * 320 + off];
        float4 vC = h[sC * 320 + off];
        float4 vD = h[sD * 320 + off];
        fma4(a0, wA, vA); fma4(a1, wB, vB); fma4(a2, wC, vC); fma4(a3, wD, vD);
    }
    for (; e < s1; ++e) fma4(a0, wts[e], h[src[e] * 320 + off]);
    a0.x += a1.x + a2.x + a3.x;
    a0.y += a1.y + a2.y + a3.y;
    a0.z += a1.z + a2.z + a3.z;
    a0.w += a1.w + a2.w + a3.w;

    size_t b0 = (size_t)n * 320 + off;
    float4 xv = y[b0];
    float4 r;
    r.x = gelu_elu(a0.x + xv.x);
    r.y = gelu_elu(a0.y + xv.y);
    r.z = gelu_elu(a0.z + xv.z);
    r.w = gelu_elu(a0.w + xv.w);
    y[b0] = r;
}

// ---------------- batched dual GEMM2: [M,20]@[20,7] x2; H2 padded to 8 ch ----------------
__global__ __launch_bounds__(256) void gemm2_all(
    const float* __restrict__ Y, const float* __restrict__ W2,
    const float* __restrict__ V2, const float* __restrict__ b2,
    float* __restrict__ H2, float* __restrict__ YV)
{
    int br = blockIdx.y;
    const float* y  = Y + (size_t)br * H1S;
    float* h2 = H2 + (size_t)br * H2S;
    float* yv = YV + (size_t)br * YVS;
    __shared__ float w2s[140], v2s[140], b2s[7];
    int t = threadIdx.x;
    if (t < 140) { w2s[t] = W2[br * 140 + t]; v2s[t] = V2[br * 140 + t]; }
    if (t < 7) b2s[t] = b2[br * 7 + t];
    __syncthreads();
    int wv = t >> 6, b = t & 63;
    int n = blockIdx.x * 4 + wv;
    size_t yb = (size_t)n * 1280 + b;
    float yr[20];
#pragma unroll
    for (int k = 0; k < 20; ++k) yr[k] = y[yb + (size_t)k * 64];
    float a[7] = {}, v[7] = {};
#pragma unroll
    for (int k = 0; k < 20; ++k) {
        float yk = yr[k];
#pragma unroll
        for (int c = 0; c < 7; ++c) {
            a[c] += yk * w2s[k * 7 + c];
            v[c] += yk * v2s[k * 7 + c];
        }
    }
    size_t hb = (size_t)n * 512 + b;
#pragma unroll
    for (int c = 0; c < 7; ++c) h2[hb + (size_t)c * 64] = a[c];
    h2[hb + 7 * 64] = 0.0f;                       // padding channel
    size_t vb = (size_t)n * 448 + b;
#pragma unroll
    for (int c = 0; c < 7; ++c) yv[vb + (size_t)c * 64] = v[c] + b2s[c];
}

// ---------------- batched SpMM2 + ReLU + softmax(B) -> per-branch P ----------------
// XCD-pinned: 12 slices (br x half-row) of 512 groups; XCD x runs w = x*768 + k.
// Row = [8 ch][64 b] = 128 float4; wave handles 64 slots: c = slot>>4, bq = lane&15.
__global__ __launch_bounds__(256) void spmm2_all(
    const float4* __restrict__ H2, const float* __restrict__ YV,
    const int* __restrict__ rowptr, const int* __restrict__ csrc, const float* __restrict__ csrw,
    float* __restrict__ P)
{
    int bid = blockIdx.x;
    int w0 = (bid & 7) * 768 + (bid >> 3);    // 0..6143
    int sl = w0 >> 9;                          // 0..11
    int ng = w0 & 511;
    int br = sl >> 1, hh = sl & 1;

    int gg = br == 1 ? 1 : br == 2 ? 2 : br == 5 ? 3 : 0;
    const int*   rp  = rowptr + gg * (NN + 1);
    const int*   src = csrc + (size_t)gg * EE;
    const float* wts = csrw + (size_t)gg * EE;
    const float4* h2 = H2 + (size_t)br * (H2S / 4);
    const float* yv = YV + (size_t)br * YVS;
    float* p = P + (size_t)br * YVS;

    int w = threadIdx.x >> 6, lane = threadIdx.x & 63;
    int n = ng * 4 + w;
    int s = hh * 64 + lane;          // float4 slot in the 128-slot row
    int c = s >> 4;                  // 0..7 (7 = padding)
    int bq = lane & 15;              // b quad
    int s0 = rp[n], s1 = rp[n + 1];

    float4 a0 = {0,0,0,0}, a1 = {0,0,0,0}, a2 = {0,0,0,0}, a3 = {0,0,0,0};
    int e = s0;
    for (; e + 4 <= s1; e += 4) {
        int   sA = src[e],     sB = src[e + 1], sC = src[e + 2], sD = src[e + 3];
        float wA = wts[e],     wB = wts[e + 1], wC = wts[e + 2], wD = wts[e + 3];
        float4 vA = h2[sA * 128 + s];
        float4 vB = h2[sB * 128 + s];
        float4 vC = h2[sC * 128 + s];
        float4 vD = h2[sD * 128 + s];
        fma4(a0, wA, vA); fma4(a1, wB, vB); fma4(a2, wC, vC); fma4(a3, wD, vD);
    }
    for (; e < s1; ++e) fma4(a0, wts[e], h2[src[e] * 128 + s]);
    a0.x += a1.x + a2.x + a3.x;
    a0.y += a1.y + a2.y + a3.y;
    a0.z += a1.z + a2.z + a3.z;
    a0.w += a1.w + a2.w + a3.w;

    float4 z = {0,0,0,0};
    if (c < 7) {
        float4 yvv = *reinterpret_cast<const float4*>(&yv[(size_t)n * 448 + c * 64 + bq * 4]);
        z.x = fmaxf(a0.x + yvv.x, 0.0f);
        z.y = fmaxf(a0.y + yvv.y, 0.0f);
        z.z = fmaxf(a0.z + yvv.z, 0.0f);
        z.w = fmaxf(a0.w + yvv.w, 0.0f);
    }
    // softmax over batch: 16 lanes (same c) x 4 components
    float m = fmaxf(fmaxf(z.x, z.y), fmaxf(z.z, z.w));
#pragma unroll
    for (int o = 8; o > 0; o >>= 1) m = fmaxf(m, __shfl_xor(m, o, 64));
    float4 pz;
    pz.x = expf(z.x - m); pz.y = expf(z.y - m);
    pz.z = expf(z.z - m); pz.w = expf(z.w - m);
    float sm = pz.x + pz.y + pz.z + pz.w;
#pragma unroll
    for (int o = 8; o > 0; o >>= 1) sm += __shfl_xor(sm, o, 64);
    float inv = 1.0f / sm;
    if (c < 7) {
        float4 r = { pz.x * inv, pz.y * inv, pz.z * inv, pz.w * inv };
        *reinterpret_cast<float4*>(&p[(size_t)n * 448 + c * 64 + bq * 4]) = r;
    }
}

// ---------------- wave softmax over 64 lanes (batch axis) ----------------
__device__ __forceinline__ void wave_softmax7(float* z)
{
#pragma unroll
    for (int c = 0; c < 7; ++c) {
        float m = z[c];
#pragma unroll
        for (int o = 32; o > 0; o >>= 1) m = fmaxf(m, __shfl_xor(m, o, 64));
        float p = expf(z[c] - m);
        float s = p;
#pragma unroll
        for (int o = 32; o > 0; o >>= 1) s += __shfl_xor(s, o, 64);
        z[c] = p / s;
    }
}

// ---------------- final: o_lt tail, dense+gnn heads, output [N][C][B] ----------------
__global__ __launch_bounds__(256) void combine_kernel(
    const float* __restrict__ T, const float* __restrict__ P,
    const float* __restrict__ Wl2, const float* __restrict__ bl2,
    const float* __restrict__ Wd, const float* __restrict__ bd,
    const float* __restrict__ Wg, const float* __restrict__ bg,
    float* __restrict__ out)
{
    __shared__ float wl2s[280], bl2s[7], wds[49], bds[7], wgs[49], bgs[7];
    int t = threadIdx.x;
    for (int i = t; i < 280; i += 256) wl2s[i] = Wl2[i];
    if (t < 49) { wds[t] = Wd[t]; wgs[t] = Wg[t]; }
    if (t < 7) { bl2s[t] = bl2[t]; bds[t] = bd[t]; bgs[t] = bg[t]; }
    __syncthreads();

    int wv = t >> 6, b = t & 63;
    int n = blockIdx.x * 4 + wv;
    size_t rbase = (size_t)n * 2560 + b;   // T is [n][40][b]
    float tr[40];
#pragma unroll
    for (int j = 0; j < 40; ++j) tr[j] = T[rbase + (size_t)j * 64];

    float u[7];
#pragma unroll
    for (int c = 0; c < 7; ++c) u[c] = bl2s[c];
    for (int j = 0; j < 40; ++j) {
        float tv = tr[j];
#pragma unroll
        for (int c = 0; c < 7; ++c) u[c] += tv * wl2s[j * 7 + c];
    }
    wave_softmax7(u);   // o_lt

    size_t sbase = (size_t)n * 448 + b;
    float sd[7], sg[7];
#pragma unroll
    for (int c = 0; c < 7; ++c) {
        size_t o = sbase + (size_t)c * 64;
        sg[c] = P[o] + P[YVS + o] + P[2 * YVS + o] + P[3 * YVS + o] + P[4 * YVS + o];
        sd[c] = 2.0f * P[5 * YVS + o] + 2.0f * u[c];
    }
    float dv[7];
#pragma unroll
    for (int c = 0; c < 7; ++c) dv[c] = bds[c];
#pragma unroll
    for (int c2 = 0; c2 < 7; ++c2) {
        float s = sd[c2];
#pragma unroll
        for (int c = 0; c < 7; ++c) dv[c] += s * wds[c2 * 7 + c];
    }
    wave_softmax7(dv);  // out_dense

    float gv[7];
#pragma unroll
    for (int c = 0; c < 7; ++c) gv[c] = bgs[c];
#pragma unroll
    for (int c2 = 0; c2 < 7; ++c2) {
        float s = sg[c2];
#pragma unroll
        for (int c = 0; c < 7; ++c) gv[c] += s * wgs[c2 * 7 + c];
    }
    wave_softmax7(gv);  // out_gnn

    size_t ob = (size_t)n * 448 + b;
#pragma unroll
    for (int c = 0; c < 7; ++c) out[ob + (size_t)c * 64] = dv[c] + gv[c];
}

// ---------------- host ----------------
extern "C" void kernel_launch(void* const* d_in, const int* in_sizes, int n_in,
                              void* d_out, int out_size, void* d_ws, size_t ws_size,
                              hipStream_t stream)
{
    (void)in_sizes; (void)n_in; (void)out_size; (void)ws_size;
    const int* e0 = (const int*)d_in[0];
    const int* e1 = (const int*)d_in[1];
    const int* e2 = (const int*)d_in[2];
    const int* e3 = (const int*)d_in[3];
    const float* X0 = (const float*)d_in[4];
    const float* X1 = (const float*)d_in[5];
    const float* X2 = (const float*)d_in[6];
    const float* X3 = (const float*)d_in[7];
    const float* X4 = (const float*)d_in[8];
    const float* X5 = (const float*)d_in[9];
    const float* W1  = (const float*)d_in[10];
    const float* V1  = (const float*)d_in[11];
    const float* b1  = (const float*)d_in[12];
    const float* W2  = (const float*)d_in[13];
    const float* V2  = (const float*)d_in[14];
    const float* b2  = (const float*)d_in[15];
    const float* Wlt = (const float*)d_in[16];
    const float* blt = (const float*)d_in[17];
    const float* Wl2 = (const float*)d_in[18];
    const float* bl2 = (const float*)d_in[19];
    const float* Wd  = (const float*)d_in[20];
    const float* bd  = (const float*)d_in[21];
    const float* Wg  = (const float*)d_in[22];
    const float* bg  = (const float*)d_in[23];

    char* ws = (char*)d_ws;
    int*   deg    = (int*)(ws + OFF_DEG);
    int*   cursor = (int*)(ws + OFF_CURSOR);
    float* dinv   = (float*)(ws + OFF_DINV);
    int*   rowptr = (int*)(ws + OFF_ROWPTR);
    int*   csrc   = (int*)(ws + OFF_CSRC);
    float* csrw   = (float*)(ws + OFF_CSRW);
    float* H1     = (float*)(ws + OFF_H1);
    float* Pbuf   = (float*)(ws + OFF_P);
    float* Y      = (float*)(ws + OFF_Y);
    float* H2     = (float*)(ws + OFF_H2);
    float* YV     = (float*)(ws + OFF_YV);
    float* Tbuf   = (float*)(ws + OFF_T);

    hipMemsetAsync(d_ws, 0, ZBYTES, stream);

    count_deg_kernel<<<1024, 256, 0, stream>>>(e0 + EE, e1 + EE, e2 + EE, e3 + EE, deg);
    scan_dinv_kernel<<<4, 256, 0, stream>>>(deg, rowptr, dinv);
    fill_csr_kernel<<<1024, 256, 0, stream>>>(e0, e0 + EE, e1, e1 + EE, e2, e2 + EE,
                                              e3, e3 + EE, rowptr, cursor, dinv, csrc, csrw);

    gemm48_all<<<dim3(512, 7), 256, 0, stream>>>(X0, X1, X2, X3, X4, X5,
                                                 W1, V1, b1, Wlt, blt, H1, Y, Tbuf);
    spmm1_all<<<15360, 256, 0, stream>>>((const float4*)H1, (float4*)Y,
                                         rowptr, csrc, csrw);
    gemm2_all<<<dim3(512, 6), 256, 0, stream>>>(Y, W2, V2, b2, H2, YV);
    spmm2_all<<<6144, 256, 0, stream>>>((const float4*)H2, YV,
                                        rowptr, csrc, csrw, Pbuf);
    combine_kernel<<<512, 256, 0, stream>>>(Tbuf, Pbuf, Wl2, bl2, Wd, bd, Wg, bg,
                                            (float*)d_out);
}

// Round 5
// 297.533 us; speedup vs baseline: 2.1725x; 1.1112x over previous
//
#include <hip/hip_runtime.h>
#include <math.h>

// Problem dims
#define NN   2048      // nodes
#define BB   64        // batch
#define FF   48        // in features
#define EE   65536     // edges per graph
#define CC   7         // out channels
#define HH   20        // hidden

// ---- ws layout (bytes), ws_size = 256 MiB ----
#define OFF_DEG      0u
#define OFF_CURSOR   32768u
#define ZBYTES       65536u
#define OFF_DINV     65536u            // float[4][N]
#define OFF_ROWPTR   98304u            // int[4][N+1]
#define OFF_CSRC     131584u           // int[4][E]
#define OFF_CSRW     1180160u          // float[4][E]
#define OFF_H1       2228736u          // 6 x float[N][20][B] = 6 x 10.49MB
#define OFF_P        OFF_H1            // 6 x float[N][7][B], overlays H1 (dead at spmm2)
#define OFF_Y        65143296u         // 6 x float[N][20][B]; init = xV+b, then act in place
#define OFF_H2       128057856u        // 6 x float[N][8][B] (padded to 8 ch) = 6 x 4MB
#define OFF_YV       153223680u        // 6 x float[N][7][B]
#define OFF_T        175243776u        // float[N][40][B] 21MB
// end = 196,215,296 B < 256 MiB

#define H1S  2621440u   // floats per branch in H1/Y
#define H2S  1048576u   // floats per branch in H2 (padded)
#define YVS  917504u    // floats per branch in YV / P

// ---------------- CSR build ----------------
__global__ __launch_bounds__(256) void count_deg_kernel(
    const int* __restrict__ c0, const int* __restrict__ c1,
    const int* __restrict__ c2, const int* __restrict__ c3, int* __restrict__ deg)
{
    int idx = blockIdx.x * 256 + threadIdx.x;          // 4*E threads
    int g = idx >> 16, e = idx & 0xFFFF;
    const int* cp = g == 0 ? c0 : g == 1 ? c1 : g == 2 ? c2 : c3;
    atomicAdd(&deg[(g << 11) + cp[e]], 1);
}

__global__ __launch_bounds__(256) void scan_dinv_kernel(
    const int* __restrict__ deg, int* __restrict__ rowptr, float* __restrict__ dinv)
{
    int g = blockIdx.x, t = threadIdx.x;
    __shared__ int part[256];
    const int* d = deg + g * NN;
    int loc[8]; int s = 0;
#pragma unroll
    for (int j = 0; j < 8; ++j) { loc[j] = d[t * 8 + j]; s += loc[j]; }
    part[t] = s; __syncthreads();
    for (int off = 1; off < 256; off <<= 1) {
        int v = (t >= off) ? part[t - off] : 0;
        __syncthreads();
        part[t] += v;
        __syncthreads();
    }
    int run = (t > 0) ? part[t - 1] : 0;
    int* rp = rowptr + g * (NN + 1);
#pragma unroll
    for (int j = 0; j < 8; ++j) {
        int n = t * 8 + j;
        rp[n] = run; run += loc[j];
        dinv[g * NN + n] = loc[j] > 0 ? 1.0f / sqrtf((float)loc[j]) : 0.0f;
    }
    if (t == 255) rp[NN] = run;
}

__global__ __launch_bounds__(256) void fill_csr_kernel(
    const int* __restrict__ r0, const int* __restrict__ c0,
    const int* __restrict__ r1, const int* __restrict__ c1,
    const int* __restrict__ r2, const int* __restrict__ c2,
    const int* __restrict__ r3, const int* __restrict__ c3,
    const int* __restrict__ rowptr, int* __restrict__ cursor,
    const float* __restrict__ dinv, int* __restrict__ csrc, float* __restrict__ cw)
{
    int idx = blockIdx.x * 256 + threadIdx.x;
    int g = idx >> 16, e = idx & 0xFFFF;
    const int* rp = g == 0 ? r0 : g == 1 ? r1 : g == 2 ? r2 : r3;
    const int* cp = g == 0 ? c0 : g == 1 ? c1 : g == 2 ? c2 : c3;
    int r = rp[e], c = cp[e];
    int pos = atomicAdd(&cursor[(g << 11) + c], 1);
    int o = rowptr[g * (NN + 1) + c] + pos;
    csrc[(g << 16) + o] = r;
    cw[(g << 16) + o] = dinv[(g << 11) + r] * dinv[(g << 11) + c];
}

// ---------------- batched dual GEMM: [M,48] @ [48,20] x2, out [n][k][b] ----------------
// xs transposed [f][row] (stride 260): per f ONE ds_read_b128 per thread.
// Weights read straight from global with wave-uniform (readfirstlane) offsets -> s_load.
__global__ __launch_bounds__(256) void gemm48_all(
    const float* __restrict__ X0, const float* __restrict__ X1,
    const float* __restrict__ X2, const float* __restrict__ X3,
    const float* __restrict__ X4, const float* __restrict__ X5,
    const float* __restrict__ W1, const float* __restrict__ V1, const float* __restrict__ b1,
    const float* __restrict__ Wlt, const float* __restrict__ blt,
    float* __restrict__ H1, float* __restrict__ Y, float* __restrict__ T)
{
    int br = blockIdx.y;
    const float* X; const float* Wa; const float* Wb; const float* ba; const float* bb;
    float* outA; float* outB; int wstride, nstride;
    if (br < 6) {
        X = br == 0 ? X0 : br == 1 ? X1 : br == 2 ? X2 : br == 3 ? X3 : br == 4 ? X4 : X5;
        Wa = W1 + br * 960; Wb = V1 + br * 960; wstride = 20;
        ba = nullptr; bb = b1 + br * 20;
        outA = H1 + (size_t)br * H1S; outB = Y + (size_t)br * H1S; nstride = 1280;
    } else {
        X = X5; Wa = Wlt; Wb = Wlt + 20; wstride = 40;
        ba = blt; bb = blt + 20;
        outA = T; outB = T + 1280; nstride = 2560;
    }

    __shared__ float xs[48 * 260];   // [f][row], stride 260 floats (1040B, 16B-aligned)
    int t = threadIdx.x;
    size_t base = (size_t)blockIdx.x * 256 * 48;

    // stage transposed: coalesced float4 global loads, scatter 4 scalar LDS writes
    {
        int fl = 4 * t;
        int r = fl / 48, f = fl % 48;
#pragma unroll
        for (int i = 0; i < 12; ++i) {
            float4 v = *reinterpret_cast<const float4*>(&X[base + (size_t)r * 48 + f]);
            xs[(f + 0) * 260 + r] = v.x;
            xs[(f + 1) * 260 + r] = v.y;
            xs[(f + 2) * 260 + r] = v.z;
            xs[(f + 3) * 260 + r] = v.w;
            r += 21; f += 16;
            if (f >= 48) { f -= 48; r += 1; }
        }
    }
    __syncthreads();

    int lane = t & 63;
    int kb = __builtin_amdgcn_readfirstlane((t >> 6) * 5);   // scalar k-group base
    const float* wap = Wa + kb;
    const float* wbp = Wb + kb;
    float bav[5], bbv[5];
#pragma unroll
    for (int j = 0; j < 5; ++j) {
        bav[j] = ba ? ba[kb + j] : 0.0f;
        bbv[j] = bb[kb + j];
    }

    float accA[5][4] = {}; float accB[5][4] = {};   // [j][row-in-quad]
    for (int f = 0; f < 48; ++f) {
        float4 x = *reinterpret_cast<const float4*>(&xs[f * 260 + 4 * lane]);
        const float* wr = wap + f * wstride;
        const float* vr = wbp + f * wstride;
#pragma unroll
        for (int j = 0; j < 5; ++j) {
            float wa = wr[j], wb = vr[j];
            accA[j][0] += wa * x.x; accA[j][1] += wa * x.y;
            accA[j][2] += wa * x.z; accA[j][3] += wa * x.w;
            accB[j][0] += wb * x.x; accB[j][1] += wb * x.y;
            accB[j][2] += wb * x.z; accB[j][3] += wb * x.w;
        }
    }

    int nd = blockIdx.x * 4 + (lane >> 4);
    int b0 = (lane & 15) * 4;
    size_t ob = (size_t)nd * nstride + b0;
#pragma unroll
    for (int j = 0; j < 5; ++j) {
        float4 va = { accA[j][0] + bav[j], accA[j][1] + bav[j],
                      accA[j][2] + bav[j], accA[j][3] + bav[j] };
        float4 vb = { accB[j][0] + bbv[j], accB[j][1] + bbv[j],
                      accB[j][2] + bbv[j], accB[j][3] + bbv[j] };
        *reinterpret_cast<float4*>(&outA[ob + (size_t)(kb + j) * 64]) = va;
        *reinterpret_cast<float4*>(&outB[ob + (size_t)(kb + j) * 64]) = vb;
    }
}

__device__ __forceinline__ void fma4(float4& a, float w, const float4 v) {
    a.x += w * v.x; a.y += w * v.y; a.z += w * v.z; a.w += w * v.w;
}
__device__ __forceinline__ float gelu_elu(float v) {
    float g = 0.5f * v * (1.0f + erff(v * 0.70710678118654752f));   // exact GELU
    return g > 0.0f ? g : expm1f(g);                                 // ELU
}

// ---------------- batched SpMM1 + GELU + ELU, in-place on Y (= xV+b) ----------------
// XCD-pinned slices; scalarized CSR (n wave-uniform via readfirstlane); 8-deep gather.
__global__ __launch_bounds__(256) void spmm1_all(
    const float4* __restrict__ H1, float4* __restrict__ Y,
    const int* __restrict__ rowptr, const int* __restrict__ csrc, const float* __restrict__ csrw)
{
    int bid = blockIdx.x;
    int w0 = (bid & 7) * 1920 + (bid >> 3);   // 0..15359
    int sl = w0 >> 9;                          // 0..29
    int ng = w0 & 511;
    int br = sl / 5, q = sl - br * 5;

    int gg = br == 1 ? 1 : br == 2 ? 2 : br == 5 ? 3 : 0;
    const int*   rp  = rowptr + gg * (NN + 1);
    const int*   src = csrc + (size_t)gg * EE;
    const float* wts = csrw + (size_t)gg * EE;
    const float4* h = H1 + (size_t)br * (H1S / 4);
    float4*       y = Y  + (size_t)br * (H1S / 4);

    int wv = __builtin_amdgcn_readfirstlane(threadIdx.x >> 6);
    int lane = threadIdx.x & 63;
    int n = ng * 4 + wv;                       // wave-uniform -> scalar CSR loads
    int off = q * 64 + lane;
    int s0 = rp[n], s1 = rp[n + 1];

    float4 a0 = {0,0,0,0}, a1 = {0,0,0,0}, a2 = {0,0,0,0}, a3 = {0,0,0,0};
    int e = s0;
    for (; e + 8 <= s1; e += 8) {
        int   iA = src[e],   iB = src[e+1], iC = src[e+2], iD = src[e+3];
        int   iE = src[e+4], iF = src[e+5], iG = src[e+6], iH = src[e+7];
        float wA = wts[e],   wB = wts[e+1], wC = wts[e+2], wD = wts[e+3];
        float wE = wts[e+4], wF = wts[e+5], wG = wts[e+6], wH = wts[e+7];
        float4 v0 = h[iA * 320 + off];
        float4 v1 = h[iB * 320 + off];
        float4 v2 = h[iC * 320 + off];
        float4 v3 = h[iD * 320 + off];
        float4 v4 = h[iE * 320 + off];
        float4 v5 = h[iF * 320 + off];
        float4 v6 = h[iG * 320 + off];
        float4 v7 = h[iH * 320 + off];
        fma4(a0, wA, v0); fma4(a1, wB, v1); fma4(a2, wC, v2); fma4(a3, wD, v3);
        fma4(a0, wE, v4); fma4(a1, wF, v5); fma4(a2, wG, v6); fma4(a3, wH, v7);
    }
    for (; e + 2 <= s1; e += 2) {
        int   iA = src[e],  iB = src[e+1];
        float wA = wts[e],  wB = wts[e+1];
        float4 v0 = h[iA * 320 + off];
        float4 v1 = h[iB * 320 + off];
        fma4(a0, wA, v0); fma4(a1, wB, v1);
    }
    if (e < s1) fma4(a0, wts[e], h[src[e] * 320 + off]);
    a0.x += a1.x + a2.x + a3.x;
    a0.y += a1.y + a2.y + a3.y;
    a0.z += a1.z + a2.z + a3.z;
    a0.w += a1.w + a2.w + a3.w;

    size_t b0 = (size_t)n * 320 + off;
    float4 xv = y[b0];
    float4 r;
    r.x = gelu_elu(a0.x + xv.x);
    r.y = gelu_elu(a0.y + xv.y);
    r.z = gelu_elu(a0.z + xv.z);
    r.w = gelu_elu(a0.w + xv.w);
    y[b0] = r;
}

// ---------------- batched dual GEMM2: [M,20]@[20,7] x2; H2 padded to 8 ch ----------------
__global__ __launch_bounds__(256) void gemm2_all(
    const float* __restrict__ Y, const float* __restrict__ W2,
    const float* __restrict__ V2, const float* __restrict__ b2,
    float* __restrict__ H2, float* __restrict__ YV)
{
    int br = blockIdx.y;
    const float* y  = Y + (size_t)br * H1S;
    float* h2 = H2 + (size_t)br * H2S;
    float* yv = YV + (size_t)br * YVS;
    __shared__ float w2s[140], v2s[140], b2s[7];
    int t = threadIdx.x;
    if (t < 140) { w2s[t] = W2[br * 140 + t]; v2s[t] = V2[br * 140 + t]; }
    if (t < 7) b2s[t] = b2[br * 7 + t];
    __syncthreads();
    int wv = __builtin_amdgcn_readfirstlane(t >> 6), b = t & 63;
    int n = blockIdx.x * 4 + wv;
    size_t yb = (size_t)n * 1280 + b;
    float yr[20];
#pragma unroll
    for (int k = 0; k < 20; ++k) yr[k] = y[yb + (size_t)k * 64];
    float a[7] = {}, v[7] = {};
#pragma unroll
    for (int k = 0; k < 20; ++k) {
        float yk = yr[k];
#pragma unroll
        for (int c = 0; c < 7; ++c) {
            a[c] += yk * w2s[k * 7 + c];
            v[c] += yk * v2s[k * 7 + c];
        }
    }
    size_t hb = (size_t)n * 512 + b;
#pragma unroll
    for (int c = 0; c < 7; ++c) h2[hb + (size_t)c * 64] = a[c];
    h2[hb + 7 * 64] = 0.0f;                       // padding channel
    size_t vb = (size_t)n * 448 + b;
#pragma unroll
    for (int c = 0; c < 7; ++c) yv[vb + (size_t)c * 64] = v[c] + b2s[c];
}

// ---------------- batched SpMM2 + ReLU + softmax(B) -> per-branch P ----------------
// XCD-pinned; scalarized CSR; 8-deep gather. Row = [8 ch][64 b] = 128 float4.
__global__ __launch_bounds__(256) void spmm2_all(
    const float4* __restrict__ H2, const float* __restrict__ YV,
    const int* __restrict__ rowptr, const int* __restrict__ csrc, const float* __restrict__ csrw,
    float* __restrict__ P)
{
    int bid = blockIdx.x;
    int w0 = (bid & 7) * 768 + (bid >> 3);    // 0..6143
    int sl = w0 >> 9;                          // 0..11
    int ng = w0 & 511;
    int br = sl >> 1, hh = sl & 1;

    int gg = br == 1 ? 1 : br == 2 ? 2 : br == 5 ? 3 : 0;
    const int*   rp  = rowptr + gg * (NN + 1);
    const int*   src = csrc + (size_t)gg * EE;
    const float* wts = csrw + (size_t)gg * EE;
    const float4* h2 = H2 + (size_t)br * (H2S / 4);
    const float* yv = YV + (size_t)br * YVS;
    float* p = P + (size_t)br * YVS;

    int wv = __builtin_amdgcn_readfirstlane(threadIdx.x >> 6);
    int lane = threadIdx.x & 63;
    int n = ng * 4 + wv;
    int s = hh * 64 + lane;          // float4 slot in the 128-slot row
    int c = s >> 4;                  // 0..7 (7 = padding)
    int bq = lane & 15;              // b quad
    int s0 = rp[n], s1 = rp[n + 1];

    float4 a0 = {0,0,0,0}, a1 = {0,0,0,0}, a2 = {0,0,0,0}, a3 = {0,0,0,0};
    int e = s0;
    for (; e + 8 <= s1; e += 8) {
        int   iA = src[e],   iB = src[e+1], iC = src[e+2], iD = src[e+3];
        int   iE = src[e+4], iF = src[e+5], iG = src[e+6], iH = src[e+7];
        float wA = wts[e],   wB = wts[e+1], wC = wts[e+2], wD = wts[e+3];
        float wE = wts[e+4], wF = wts[e+5], wG = wts[e+6], wH = wts[e+7];
        float4 v0 = h2[iA * 128 + s];
        float4 v1 = h2[iB * 128 + s];
        float4 v2 = h2[iC * 128 + s];
        float4 v3 = h2[iD * 128 + s];
        float4 v4 = h2[iE * 128 + s];
        float4 v5 = h2[iF * 128 + s];
        float4 v6 = h2[iG * 128 + s];
        float4 v7 = h2[iH * 128 + s];
        fma4(a0, wA, v0); fma4(a1, wB, v1); fma4(a2, wC, v2); fma4(a3, wD, v3);
        fma4(a0, wE, v4); fma4(a1, wF, v5); fma4(a2, wG, v6); fma4(a3, wH, v7);
    }
    for (; e < s1; ++e) fma4(a0, wts[e], h2[src[e] * 128 + s]);
    a0.x += a1.x + a2.x + a3.x;
    a0.y += a1.y + a2.y + a3.y;
    a0.z += a1.z + a2.z + a3.z;
    a0.w += a1.w + a2.w + a3.w;

    float4 z = {0,0,0,0};
    if (c < 7) {
        float4 yvv = *reinterpret_cast<const float4*>(&yv[(size_t)n * 448 + c * 64 + bq * 4]);
        z.x = fmaxf(a0.x + yvv.x, 0.0f);
        z.y = fmaxf(a0.y + yvv.y, 0.0f);
        z.z = fmaxf(a0.z + yvv.z, 0.0f);
        z.w = fmaxf(a0.w + yvv.w, 0.0f);
    }
    // softmax over batch: 16 lanes (same c) x 4 components
    float m = fmaxf(fmaxf(z.x, z.y), fmaxf(z.z, z.w));
#pragma unroll
    for (int o = 8; o > 0; o >>= 1) m = fmaxf(m, __shfl_xor(m, o, 64));
    float4 pz;
    pz.x = expf(z.x - m); pz.y = expf(z.y - m);
    pz.z = expf(z.z - m); pz.w = expf(z.w - m);
    float sm = pz.x + pz.y + pz.z + pz.w;
#pragma unroll
    for (int o = 8; o > 0; o >>= 1) sm += __shfl_xor(sm, o, 64);
    float inv = 1.0f / sm;
    if (c < 7) {
        float4 r = { pz.x * inv, pz.y * inv, pz.z * inv, pz.w * inv };
        *reinterpret_cast<float4*>(&p[(size_t)n * 448 + c * 64 + bq * 4]) = r;
    }
}

// ---------------- wave softmax over 64 lanes (batch axis) ----------------
__device__ __forceinline__ void wave_softmax7(float* z)
{
#pragma unroll
    for (int c = 0; c < 7; ++c) {
        float m = z[c];
#pragma unroll
        for (int o = 32; o > 0; o >>= 1) m = fmaxf(m, __shfl_xor(m, o, 64));
        float p = expf(z[c] - m);
        float s = p;
#pragma unroll
        for (int o = 32; o > 0; o >>= 1) s += __shfl_xor(s, o, 64);
        z[c] = p / s;
    }
}

// ---------------- final: o_lt tail, dense+gnn heads, output [N][C][B] ----------------
__global__ __launch_bounds__(256) void combine_kernel(
    const float* __restrict__ T, const float* __restrict__ P,
    const float* __restrict__ Wl2, const float* __restrict__ bl2,
    const float* __restrict__ Wd, const float* __restrict__ bd,
    const float* __restrict__ Wg, const float* __restrict__ bg,
    float* __restrict__ out)
{
    __shared__ float wl2s[280], bl2s[7], wds[49], bds[7], wgs[49], bgs[7];
    int t = threadIdx.x;
    for (int i = t; i < 280; i += 256) wl2s[i] = Wl2[i];
    if (t < 49) { wds[t] = Wd[t]; wgs[t] = Wg[t]; }
    if (t < 7) { bl2s[t] = bl2[t]; bds[t] = bd[t]; bgs[t] = bg[t]; }
    __syncthreads();

    int wv = t >> 6, b = t & 63;
    int n = blockIdx.x * 4 + wv;
    size_t rbase = (size_t)n * 2560 + b;   // T is [n][40][b]
    float tr[40];
#pragma unroll
    for (int j = 0; j < 40; ++j) tr[j] = T[rbase + (size_t)j * 64];

    float u[7];
#pragma unroll
    for (int c = 0; c < 7; ++c) u[c] = bl2s[c];
    for (int j = 0; j < 40; ++j) {
        float tv = tr[j];
#pragma unroll
        for (int c = 0; c < 7; ++c) u[c] += tv * wl2s[j * 7 + c];
    }
    wave_softmax7(u);   // o_lt

    size_t sbase = (size_t)n * 448 + b;
    float sd[7], sg[7];
#pragma unroll
    for (int c = 0; c < 7; ++c) {
        size_t o = sbase + (size_t)c * 64;
        sg[c] = P[o] + P[YVS + o] + P[2 * YVS + o] + P[3 * YVS + o] + P[4 * YVS + o];
        sd[c] = 2.0f * P[5 * YVS + o] + 2.0f * u[c];
    }
    float dv[7];
#pragma unroll
    for (int c = 0; c < 7; ++c) dv[c] = bds[c];
#pragma unroll
    for (int c2 = 0; c2 < 7; ++c2) {
        float s = sd[c2];
#pragma unroll
        for (int c = 0; c < 7; ++c) dv[c] += s * wds[c2 * 7 + c];
    }
    wave_softmax7(dv);  // out_dense

    float gv[7];
#pragma unroll
    for (int c = 0; c < 7; ++c) gv[c] = bgs[c];
#pragma unroll
    for (int c2 = 0; c2 < 7; ++c2) {
        float s = sg[c2];
#pragma unroll
        for (int c = 0; c < 7; ++c) gv[c] += s * wgs[c2 * 7 + c];
    }
    wave_softmax7(gv);  // out_gnn

    size_t ob = (size_t)n * 448 + b;
#pragma unroll
    for (int c = 0; c < 7; ++c) out[ob + (size_t)c * 64] = dv[c] + gv[c];
}

// ---------------- host ----------------
extern "C" void kernel_launch(void* const* d_in, const int* in_sizes, int n_in,
                              void* d_out, int out_size, void* d_ws, size_t ws_size,
                              hipStream_t stream)
{
    (void)in_sizes; (void)n_in; (void)out_size; (void)ws_size;
    const int* e0 = (const int*)d_in[0];
    const int* e1 = (const int*)d_in[1];
    const int* e2 = (const int*)d_in[2];
    const int* e3 = (const int*)d_in[3];
    const float* X0 = (const float*)d_in[4];
    const float* X1 = (const float*)d_in[5];
    const float* X2 = (const float*)d_in[6];
    const float* X3 = (const float*)d_in[7];
    const float* X4 = (const float*)d_in[8];
    const float* X5 = (const float*)d_in[9];
    const float* W1  = (const float*)d_in[10];
    const float* V1  = (const float*)d_in[11];
    const float* b1  = (const float*)d_in[12];
    const float* W2  = (const float*)d_in[13];
    const float* V2  = (const float*)d_in[14];
    const float* b2  = (const float*)d_in[15];
    const float* Wlt = (const float*)d_in[16];
    const float* blt = (const float*)d_in[17];
    const float* Wl2 = (const float*)d_in[18];
    const float* bl2 = (const float*)d_in[19];
    const float* Wd  = (const float*)d_in[20];
    const float* bd  = (const float*)d_in[21];
    const float* Wg  = (const float*)d_in[22];
    const float* bg  = (const float*)d_in[23];

    char* ws = (char*)d_ws;
    int*   deg    = (int*)(ws + OFF_DEG);
    int*   cursor = (int*)(ws + OFF_CURSOR);
    float* dinv   = (float*)(ws + OFF_DINV);
    int*   rowptr = (int*)(ws + OFF_ROWPTR);
    int*   csrc   = (int*)(ws + OFF_CSRC);
    float* csrw   = (float*)(ws + OFF_CSRW);
    float* H1     = (float*)(ws + OFF_H1);
    float* Pbuf   = (float*)(ws + OFF_P);
    float* Y      = (float*)(ws + OFF_Y);
    float* H2     = (float*)(ws + OFF_H2);
    float* YV     = (float*)(ws + OFF_YV);
    float* Tbuf   = (float*)(ws + OFF_T);

    hipMemsetAsync(d_ws, 0, ZBYTES, stream);

    count_deg_kernel<<<1024, 256, 0, stream>>>(e0 + EE, e1 + EE, e2 + EE, e3 + EE, deg);
    scan_dinv_kernel<<<4, 256, 0, stream>>>(deg, rowptr, dinv);
    fill_csr_kernel<<<1024, 256, 0, stream>>>(e0, e0 + EE, e1, e1 + EE, e2, e2 + EE,
                                              e3, e3 + EE, rowptr, cursor, dinv, csrc, csrw);

    gemm48_all<<<dim3(512, 7), 256, 0, stream>>>(X0, X1, X2, X3, X4, X5,
                                                 W1, V1, b1, Wlt, blt, H1, Y, Tbuf);
    spmm1_all<<<15360, 256, 0, stream>>>((const float4*)H1, (float4*)Y,
                                         rowptr, csrc, csrw);
    gemm2_all<<<dim3(512, 6), 256, 0, stream>>>(Y, W2, V2, b2, H2, YV);
    spmm2_all<<<6144, 256, 0, stream>>>((const float4*)H2, YV,
                                        rowptr, csrc, csrw, Pbuf);
    combine_kernel<<<512, 256, 0, stream>>>(Tbuf, Pbuf, Wl2, bl2, Wd, bd, Wg, bg,
                                            (float*)d_out);
}